// Round 11
// baseline (61.300 us; speedup 1.0000x reference)
//
#include <hip/hip_runtime.h>
#include <math.h>

typedef __attribute__((ext_vector_type(8))) short bf8;    // 8 x bf16 (bit pattern)
typedef __attribute__((ext_vector_type(4))) short s4v;    // 4 x bf16 (8B store)
typedef __attribute__((ext_vector_type(16))) float f16v;  // MFMA 32x32 accum
typedef __attribute__((ext_vector_type(4))) float f4v;
typedef __attribute__((ext_vector_type(4))) int i4v;

constexpr int CS = 2048;
constexpr float EPS = 1e-5f;
constexpr float LOG2E = 1.44269504088896f;

static __device__ inline short f2bf(float x) {
  union { float f; unsigned u; } v; v.f = x;
  unsigned r = (v.u + 0x7FFFu + ((v.u >> 16) & 1u)) >> 16;  // RNE
  return (short)r;
}
static __device__ inline float bf2f(short u) {
  union { unsigned u; float f; } v;
  v.u = ((unsigned)(unsigned short)u) << 16;
  return v.f;
}
static __device__ inline unsigned cvt_pk_bf16(float lo, float hi) {
  unsigned d;
  asm("v_cvt_pk_bf16_f32 %0, %1, %2" : "=v"(d) : "v"(lo), "v"(hi));
  return d;
}

// ---------------- fused LN + QKV projections (MFMA), in-block W transpose, frag-major outputs ----------------
// Qf/Kf frag-major [bh][strip32][ks][lane][8]; Vf frag-major pre-scaled by exp(-g*k2/8); aq f32 [bh][s]
__global__ __launch_bounds__(256) void k_qkv(const float* __restrict__ x, const float* __restrict__ ln_w,
                                             const float* __restrict__ Wq, const float* __restrict__ Wk,
                                             const float* __restrict__ Wv, const float* __restrict__ gamma,
                                             short* __restrict__ Qf, short* __restrict__ Kf,
                                             short* __restrict__ Vf, float* __restrict__ aqg) {
  __shared__ short WtL[3 * 64 * 72];   // [w][f][e pad72] bf16 — per-block transposed weights
  __shared__ short QtL[2 * 32 * 72];   // [strip][s 32][f pad72]
  __shared__ short KtL[2 * 32 * 72];
  __shared__ float q2s[64];
  __shared__ float bks[64];            // exp2(cgk * k2[row])
  int blk = blockIdx.x;
  int bh = blk & 15, st = blk >> 4;
  int b = bh >> 3, h = bh & 7;
  int t = threadIdx.x, wid = t >> 6, lane = t & 63;
  int l31 = lane & 31, g = lane >> 5;
  int sh = wid >> 1, fh = wid & 1;
  int f = fh * 32 + l31;

  // ---- cooperative W transpose -> WtL (4x4 subtile per thread per matrix; weights L2-hot) ----
  {
    int e0 = (t >> 4) * 4, f0 = (t & 15) * 4;
    const float* srcs[3];
    srcs[0] = Wq + h * 4096; srcs[1] = Wk + h * 4096; srcs[2] = Wv + h * 4096;
#pragma unroll
    for (int wsel = 0; wsel < 3; ++wsel) {
      const float* src = srcs[wsel];
      f4v r0 = *(const f4v*)&src[(e0 + 0) * 64 + f0];
      f4v r1 = *(const f4v*)&src[(e0 + 1) * 64 + f0];
      f4v r2 = *(const f4v*)&src[(e0 + 2) * 64 + f0];
      f4v r3 = *(const f4v*)&src[(e0 + 3) * 64 + f0];
      short* dst = &WtL[wsel * 4608];
      s4v c0, c1, c2, c3;
      c0[0] = f2bf(r0.x); c0[1] = f2bf(r1.x); c0[2] = f2bf(r2.x); c0[3] = f2bf(r3.x);
      c1[0] = f2bf(r0.y); c1[1] = f2bf(r1.y); c1[2] = f2bf(r2.y); c1[3] = f2bf(r3.y);
      c2[0] = f2bf(r0.z); c2[1] = f2bf(r1.z); c2[2] = f2bf(r2.z); c2[3] = f2bf(r3.z);
      c3[0] = f2bf(r0.w); c3[1] = f2bf(r1.w); c3[2] = f2bf(r2.w); c3[3] = f2bf(r3.w);
      *(s4v*)&dst[(f0 + 0) * 72 + e0] = c0;
      *(s4v*)&dst[(f0 + 1) * 72 + e0] = c1;
      *(s4v*)&dst[(f0 + 2) * 72 + e0] = c2;
      *(s4v*)&dst[(f0 + 3) * 72 + e0] = c3;
    }
  }

  // ---- in-register LayerNorm over this lane's row ----
  int row = b * CS + st * 64 + sh * 32 + l31;
  f4v xv[8];
#pragma unroll
  for (int ks = 0; ks < 4; ++ks) {
    xv[2 * ks]     = *(const f4v*)&x[row * 64 + ks * 16 + g * 8];
    xv[2 * ks + 1] = *(const f4v*)&x[row * 64 + ks * 16 + g * 8 + 4];
  }
  float s = 0.f;
#pragma unroll
  for (int m = 0; m < 8; ++m) s += xv[m].x + xv[m].y + xv[m].z + xv[m].w;
  s += __shfl_xor(s, 32, 64);
  float mu = s * (1.f / 64.f);
  float vs = 0.f;
#pragma unroll
  for (int m = 0; m < 8; ++m) {
#pragma unroll
    for (int j = 0; j < 4; ++j) { float d = xv[m][j] - mu; vs += d * d; }
  }
  vs += __shfl_xor(vs, 32, 64);
  float rs = rsqrtf(vs * (1.f / 64.f) + EPS);
  bf8 af[4];
#pragma unroll
  for (int ks = 0; ks < 4; ++ks) {
    f4v lw0 = *(const f4v*)&ln_w[ks * 16 + g * 8];
    f4v lw1 = *(const f4v*)&ln_w[ks * 16 + g * 8 + 4];
#pragma unroll
    for (int j = 0; j < 4; ++j) {
      af[ks][j]     = f2bf((xv[2 * ks][j] - mu) * rs * lw0[j]);
      af[ks][j + 4] = f2bf((xv[2 * ks + 1][j] - mu) * rs * lw1[j]);
    }
  }
  float gh = gamma[h];
  float cgk = -gh * 0.125f * LOG2E;  // -gamma/8 in log2 domain
  __syncthreads();                   // WtL ready

  // ---- Q -> LDS tile ----
  f16v cq; for (int i = 0; i < 16; ++i) cq[i] = 0.f;
#pragma unroll
  for (int ks = 0; ks < 4; ++ks) {
    bf8 bw = *(const bf8*)&WtL[0 * 4608 + f * 72 + ks * 16 + g * 8];
    cq = __builtin_amdgcn_mfma_f32_32x32x16_bf16(af[ks], bw, cq, 0, 0, 0);
  }
#pragma unroll
  for (int r = 0; r < 16; ++r) {
    int rl = (r & 3) + 8 * (r >> 2) + 4 * g;
    QtL[(sh * 32 + rl) * 72 + f] = f2bf(cq[r]);
  }
  // ---- K -> LDS tile ----
  f16v ck; for (int i = 0; i < 16; ++i) ck[i] = 0.f;
#pragma unroll
  for (int ks = 0; ks < 4; ++ks) {
    bf8 bw = *(const bf8*)&WtL[1 * 4608 + f * 72 + ks * 16 + g * 8];
    ck = __builtin_amdgcn_mfma_f32_32x32x16_bf16(af[ks], bw, ck, 0, 0, 0);
  }
#pragma unroll
  for (int r = 0; r < 16; ++r) {
    int rl = (r & 3) + 8 * (r >> 2) + 4 * g;
    KtL[(sh * 32 + rl) * 72 + f] = f2bf(ck[r]);
  }
  // ---- V (stays in regs) ----
  f16v cv; for (int i = 0; i < 16; ++i) cv[i] = 0.f;
#pragma unroll
  for (int ks = 0; ks < 4; ++ks) {
    bf8 bw = *(const bf8*)&WtL[2 * 4608 + f * 72 + ks * 16 + g * 8];
    cv = __builtin_amdgcn_mfma_f32_32x32x16_bf16(af[ks], bw, cv, 0, 0, 0);
  }
  __syncthreads();

  // ---- cooperative q2/k2 (4 threads/row) + per-row bk = exp2(cgk*k2) ----
  {
    int rw = t >> 2, q4 = t & 3;
    float sq = 0.f, sk = 0.f;
#pragma unroll
    for (int m = 0; m < 2; ++m) {
      bf8 vq = *(bf8*)&QtL[rw * 72 + q4 * 16 + m * 8];
      bf8 vk = *(bf8*)&KtL[rw * 72 + q4 * 16 + m * 8];
#pragma unroll
      for (int j = 0; j < 8; ++j) {
        float xq = bf2f(vq[j]); sq += xq * xq;
        float xk = bf2f(vk[j]); sk += xk * xk;
      }
    }
    sq += __shfl_xor(sq, 1, 64); sq += __shfl_xor(sq, 2, 64);
    sk += __shfl_xor(sk, 1, 64); sk += __shfl_xor(sk, 2, 64);
    if (q4 == 0) {
      q2s[rw] = sq;
      bks[rw] = exp2f(cgk * sk);
    }
  }
  // ---- cooperative packed frag-major stores: Qf and Kf [bh][strip][ks][lane][8], 4x8B each ----
  {
    int ktloc = t >> 7, lm = (t >> 1) & 63, jh = t & 1;
#pragma unroll
    for (int ks = 0; ks < 4; ++ks) {
      int laddr = (ktloc * 32 + (lm & 31)) * 72 + ks * 16 + (lm >> 5) * 8 + jh * 4;
      int gaddr = ((bh * 64 + st * 2 + ktloc) * 4 + ks) * 512 + lm * 8 + jh * 4;
      *(s4v*)&Qf[gaddr] = *(s4v*)&QtL[laddr];
      *(s4v*)&Kf[gaddr] = *(s4v*)&KtL[laddr];
    }
  }
  __syncthreads();

  // ---- V' -> frag-major Vf[bh][kt][eh][ks2][lane][8], scaled by bks[row] ----
  int kt = st * 2 + sh;
#pragma unroll
  for (int m = 0; m < 4; ++m) {
    s4v pk;
#pragma unroll
    for (int c = 0; c < 4; ++c) {
      int rl = sh * 32 + c + 8 * m + 4 * g;
      pk[c] = f2bf(cv[m * 4 + c] * bks[rl]);
    }
    int addr = ((((bh * 64 + kt) * 2 + fh) * 2 + (m >> 1)) * 64 + (m & 1) * 32 + l31) * 8 + 4 * g;
    *(s4v*)&Vf[addr] = pk;
  }
  if (t < 64) {
    aqg[bh * CS + st * 64 + t] = exp2f(cgk * q2s[t]);
  }
}

// ---------------- fused causal RBF attention (MFMA, 2 strips/wave, 512 thr, 16 waves/CU) ----------------
// Block = (bh, 64-row q-block = strips 2u,2u+1); 8 waves split k-range; each wave serves BOTH strips
// from one K/V frag load (halves L2 traffic). Sweep-balanced: CU pair (bid, bid+256) sums 66 tiles.
__global__ __launch_bounds__(512, 4) void k_attn(const short* __restrict__ Qf, const short* __restrict__ Kf,
                                                 const short* __restrict__ Vf, const float* __restrict__ aqg,
                                                 const float* __restrict__ gamma, short* __restrict__ attnB) {
  __shared__ float red4[4][64][37];
  int bid = blockIdx.x;
  int bh = ((bid & 7) << 1) | ((bid >> 3) & 1);  // bh pinned per XCD (L2 locality)
  int z = bid >> 4;                              // 0..31
  int u = (z < 16) ? (31 - z) : (z - 16);        // sweep pair (z, z+16) -> (31-z, z): sums 66 tiles
  int qtA = 2 * u, qtB = 2 * u + 1;              // 32-row strip indices
  int b = bh >> 3, h = bh & 7;
  int t = threadIdx.x, w = t >> 6, lane = t & 63;
  int lam = lane & 31, g = lane >> 5;
  float cg = gamma[h] * 0.25f * LOG2E;           // +gamma/4 in log2 domain
  int L = qtB + 1;
  int lo = (w * L) >> 3, hi = ((w + 1) * L) >> 3;

  // Q B-frags for both strips: coalesced 1KB loads from frag-major Qf
  bf8 qfA[4], qfB[4];
#pragma unroll
  for (int ks = 0; ks < 4; ++ks) {
    qfA[ks] = *(const bf8*)&Qf[((bh * 64 + qtA) * 4 + ks) * 512 + lane * 8];
    qfB[ks] = *(const bf8*)&Qf[((bh * 64 + qtB) * 4 + ks) * 512 + lane * 8];
  }

  f16v oaA0, oaA1, oaB0, oaB1;
#pragma unroll
  for (int rr = 0; rr < 16; ++rr) { oaA0[rr] = 0.f; oaA1[rr] = 0.f; oaB0[rr] = 0.f; oaB1[rr] = 0.f; }

  const short* kfb = Kf + bh * 131072 + lane * 8;
  const short* vfb = Vf + bh * 131072 + lane * 8;

  for (int kt = lo; kt < hi; ++kt) {
    // K frags: 4 fully-coalesced 1KB loads, shared by both strips
    const short* kp = kfb + kt * 2048;
    bf8 ak0 = *(const bf8*)(kp);
    bf8 ak1 = *(const bf8*)(kp + 512);
    bf8 ak2 = *(const bf8*)(kp + 1024);
    bf8 ak3 = *(const bf8*)(kp + 1536);
    bool doA = (kt <= qtA);

    // ---- QK for both strips ----
    f16v ctA, ctB;
#pragma unroll
    for (int rr = 0; rr < 16; ++rr) { ctA[rr] = 0.f; ctB[rr] = 0.f; }
    __builtin_amdgcn_s_setprio(1);
    if (doA) {
      ctA = __builtin_amdgcn_mfma_f32_32x32x16_bf16(ak0, qfA[0], ctA, 0, 0, 0);
      ctA = __builtin_amdgcn_mfma_f32_32x32x16_bf16(ak1, qfA[1], ctA, 0, 0, 0);
      ctA = __builtin_amdgcn_mfma_f32_32x32x16_bf16(ak2, qfA[2], ctA, 0, 0, 0);
      ctA = __builtin_amdgcn_mfma_f32_32x32x16_bf16(ak3, qfA[3], ctA, 0, 0, 0);
    }
    ctB = __builtin_amdgcn_mfma_f32_32x32x16_bf16(ak0, qfB[0], ctB, 0, 0, 0);
    ctB = __builtin_amdgcn_mfma_f32_32x32x16_bf16(ak1, qfB[1], ctB, 0, 0, 0);
    ctB = __builtin_amdgcn_mfma_f32_32x32x16_bf16(ak2, qfB[2], ctB, 0, 0, 0);
    ctB = __builtin_amdgcn_mfma_f32_32x32x16_bf16(ak3, qfB[3], ctB, 0, 0, 0);
    __builtin_amdgcn_s_setprio(0);

    // V frags issued here: latency hides under the exp/pack VALU phase
    const short* vp = vfb + kt * 2048;
    bf8 av00 = *(const bf8*)(vp);
    bf8 av01 = *(const bf8*)(vp + 512);
    bf8 av10 = *(const bf8*)(vp + 1024);
    bf8 av11 = *(const bf8*)(vp + 1536);

    // ---- exp + causal mask + pack, strip A then strip B ----
    unsigned pA0[4], pA1[4], pB0[4], pB1[4];
    if (doA) {
      bool dgA = (kt == qtA);
#pragma unroll
      for (int m = 0; m < 4; ++m) {
        float sv[4];
#pragma unroll
        for (int ii = 0; ii < 4; ++ii) {
          int kloc = ii + 8 * m + 4 * g;
          float ev = exp2f(cg * ctA[4 * m + ii]);
          if (dgA && kloc > lam) ev = 0.f;
          sv[ii] = ev;
        }
        pA0[m] = cvt_pk_bf16(sv[0], sv[1]);
        pA1[m] = cvt_pk_bf16(sv[2], sv[3]);
      }
    }
    {
      bool dgB = (kt == qtB);
#pragma unroll
      for (int m = 0; m < 4; ++m) {
        float sv[4];
#pragma unroll
        for (int ii = 0; ii < 4; ++ii) {
          int kloc = ii + 8 * m + 4 * g;
          float ev = exp2f(cg * ctB[4 * m + ii]);
          if (dgB && kloc > lam) ev = 0.f;
          sv[ii] = ev;
        }
        pB0[m] = cvt_pk_bf16(sv[0], sv[1]);
        pB1[m] = cvt_pk_bf16(sv[2], sv[3]);
      }
    }
    // ---- PV for both strips (shared V frags) ----
    __builtin_amdgcn_s_setprio(1);
    if (doA) {
#pragma unroll
      for (int ks2 = 0; ks2 < 2; ++ks2) {
        unsigned sendA = g ? pA0[2 * ks2] : pA0[2 * ks2 + 1];
        unsigned recvA = (unsigned)__shfl_xor((int)sendA, 32, 64);
        unsigned sendB = g ? pA1[2 * ks2] : pA1[2 * ks2 + 1];
        unsigned recvB = (unsigned)__shfl_xor((int)sendB, 32, 64);
        i4v wv;
        wv.x = g ? (int)recvA : (int)pA0[2 * ks2];
        wv.y = g ? (int)recvB : (int)pA1[2 * ks2];
        wv.z = g ? (int)pA0[2 * ks2 + 1] : (int)recvA;
        wv.w = g ? (int)pA1[2 * ks2 + 1] : (int)recvB;
        bf8 bs = *(bf8*)&wv;
        oaA0 = __builtin_amdgcn_mfma_f32_32x32x16_bf16(ks2 ? av01 : av00, bs, oaA0, 0, 0, 0);
        oaA1 = __builtin_amdgcn_mfma_f32_32x32x16_bf16(ks2 ? av11 : av10, bs, oaA1, 0, 0, 0);
      }
    }
#pragma unroll
    for (int ks2 = 0; ks2 < 2; ++ks2) {
      unsigned sendA = g ? pB0[2 * ks2] : pB0[2 * ks2 + 1];
      unsigned recvA = (unsigned)__shfl_xor((int)sendA, 32, 64);
      unsigned sendB = g ? pB1[2 * ks2] : pB1[2 * ks2 + 1];
      unsigned recvB = (unsigned)__shfl_xor((int)sendB, 32, 64);
      i4v wv;
      wv.x = g ? (int)recvA : (int)pB0[2 * ks2];
      wv.y = g ? (int)recvB : (int)pB1[2 * ks2];
      wv.z = g ? (int)pB0[2 * ks2 + 1] : (int)recvA;
      wv.w = g ? (int)pB1[2 * ks2 + 1] : (int)recvB;
      bf8 bs = *(bf8*)&wv;
      oaB0 = __builtin_amdgcn_mfma_f32_32x32x16_bf16(ks2 ? av01 : av00, bs, oaB0, 0, 0, 0);
      oaB1 = __builtin_amdgcn_mfma_f32_32x32x16_bf16(ks2 ? av11 : av10, bs, oaB1, 0, 0, 0);
    }
    __builtin_amdgcn_s_setprio(0);
  }

  // ---- epilogue: 8-way reduce + aq + store, strip A then strip B ----
  if (w < 4) {
#pragma unroll
    for (int rr = 0; rr < 16; ++rr) {
      int e = (rr & 3) + 8 * (rr >> 2) + 4 * g;
      red4[w][e][lam] = oaA0[rr];
      red4[w][e + 32][lam] = oaA1[rr];
    }
  }
  __syncthreads();
  if (w >= 4) {
#pragma unroll
    for (int rr = 0; rr < 16; ++rr) {
      int e = (rr & 3) + 8 * (rr >> 2) + 4 * g;
      red4[w - 4][e][lam] += oaA0[rr];
      red4[w - 4][e + 32][lam] += oaA1[rr];
    }
  }
  __syncthreads();
  {
    int q = t >> 4, e0 = (t & 15) * 4;
    float aqv = aqg[bh * CS + qtA * 32 + q];
    s4v ov;
#pragma unroll
    for (int jj = 0; jj < 4; ++jj) {
      float v = red4[0][e0 + jj][q] + red4[1][e0 + jj][q] + red4[2][e0 + jj][q] + red4[3][e0 + jj][q];
      ov[jj] = f2bf(v * aqv);
    }
    *(s4v*)&attnB[(b * CS + qtA * 32 + q) * 512 + h * 64 + e0] = ov;
  }
  __syncthreads();
  if (w < 4) {
#pragma unroll
    for (int rr = 0; rr < 16; ++rr) {
      int e = (rr & 3) + 8 * (rr >> 2) + 4 * g;
      red4[w][e][lam] = oaB0[rr];
      red4[w][e + 32][lam] = oaB1[rr];
    }
  }
  __syncthreads();
  if (w >= 4) {
#pragma unroll
    for (int rr = 0; rr < 16; ++rr) {
      int e = (rr & 3) + 8 * (rr >> 2) + 4 * g;
      red4[w - 4][e][lam] += oaB0[rr];
      red4[w - 4][e + 32][lam] += oaB1[rr];
    }
  }
  __syncthreads();
  {
    int q = t >> 4, e0 = (t & 15) * 4;
    float aqv = aqg[bh * CS + qtB * 32 + q];
    s4v ov;
#pragma unroll
    for (int jj = 0; jj < 4; ++jj) {
      float v = red4[0][e0 + jj][q] + red4[1][e0 + jj][q] + red4[2][e0 + jj][q] + red4[3][e0 + jj][q];
      ov[jj] = f2bf(v * aqv);
    }
    *(s4v*)&attnB[(b * CS + qtB * 32 + q) * 512 + h * 64 + e0] = ov;
  }
}

// ---------------- output projection (MFMA, 256 blocks, direct f32 Wo with in-reg bf16 cast) ----------------
__global__ __launch_bounds__(256) void k_proj(const short* __restrict__ attnB, const float* __restrict__ Wo,
                                              float* __restrict__ out) {
  __shared__ float red[4][32][36];
  int blk = blockIdx.x, t = threadIdx.x;
  int rt = blk >> 1, fh2 = blk & 1;
  int r0 = rt * 32;
  int kw = t >> 6, lane = t & 63, l31 = lane & 31, g = lane >> 5;
  f16v c; for (int i = 0; i < 16; ++i) c[i] = 0.f;
  int arow = (r0 + l31) * 512;
  int fw = fh2 * 32 + l31;           // Wo row (output feature)
#pragma unroll
  for (int ks = 0; ks < 8; ++ks) {
    int k0 = kw * 128 + ks * 16 + g * 8;
    bf8 a = *(const bf8*)&attnB[arow + k0];
    f4v w0 = *(const f4v*)&Wo[fw * 512 + k0];
    f4v w1 = *(const f4v*)&Wo[fw * 512 + k0 + 4];
    i4v wp;
    wp.x = (int)cvt_pk_bf16(w0.x, w0.y);
    wp.y = (int)cvt_pk_bf16(w0.z, w0.w);
    wp.z = (int)cvt_pk_bf16(w1.x, w1.y);
    wp.w = (int)cvt_pk_bf16(w1.z, w1.w);
    bf8 bw = *(bf8*)&wp;
    c = __builtin_amdgcn_mfma_f32_32x32x16_bf16(a, bw, c, 0, 0, 0);
  }
#pragma unroll
  for (int rr = 0; rr < 16; ++rr) {
    int rw = (rr & 3) + 8 * (rr >> 2) + 4 * g;
    red[kw][rw][l31] = c[rr];
  }
  __syncthreads();
  {
    int rw = t >> 3, f4 = (t & 7) * 4;
    f4v sum;
#pragma unroll
    for (int j = 0; j < 4; ++j)
      sum[j] = red[0][rw][f4 + j] + red[1][rw][f4 + j] + red[2][rw][f4 + j] + red[3][rw][f4 + j];
    *(f4v*)&out[(r0 + rw) * 64 + fh2 * 32 + f4] = sum;
  }
}

extern "C" void kernel_launch(void* const* d_in, const int* in_sizes, int n_in,
                              void* d_out, int out_size, void* d_ws, size_t ws_size,
                              hipStream_t stream) {
  const float* x     = (const float*)d_in[0];
  const float* ln_w  = (const float*)d_in[1];
  const float* Wq    = (const float*)d_in[2];
  const float* Wk    = (const float*)d_in[3];
  const float* Wv    = (const float*)d_in[4];
  const float* Wo    = (const float*)d_in[5];
  const float* gamma = (const float*)d_in[6];
  float* out = (float*)d_out;

  char* w = (char*)d_ws;
  short* Qf    = (short*)w;                               // 4 MB frag-major Q
  short* Kf    = (short*)(w + 4194304);                   // 4 MB frag-major K
  short* Vf    = (short*)(w + 2 * 4194304);               // 4 MB frag-major V'
  float* aqg   = (float*)(w + 3 * 4194304);               // 128 KB
  short* attnB = (short*)(w + 3 * 4194304 + 131072);      // 4 MB

  hipLaunchKernelGGL(k_qkv,  dim3(512), dim3(256), 0, stream, x, ln_w, Wq, Wk, Wv, gamma, Qf, Kf, Vf, aqg);
  hipLaunchKernelGGL(k_attn, dim3(512), dim3(512), 0, stream, Qf, Kf, Vf, aqg, gamma, attnB);
  hipLaunchKernelGGL(k_proj, dim3(256), dim3(256), 0, stream, attnB, Wo, out);
}

// Round 12
// 41.928 us; speedup vs baseline: 1.4620x; 1.4620x over previous
//
#include <hip/hip_runtime.h>
#include <math.h>

typedef __attribute__((ext_vector_type(8))) short bf8;    // 8 x bf16 (bit pattern)
typedef __attribute__((ext_vector_type(4))) short s4v;    // 4 x bf16 (8B store)
typedef __attribute__((ext_vector_type(16))) float f16v;  // MFMA 32x32 accum
typedef __attribute__((ext_vector_type(4))) float f4v;
typedef __attribute__((ext_vector_type(4))) int i4v;

constexpr int CS = 2048;
constexpr float EPS = 1e-5f;
constexpr float LOG2E = 1.44269504088896f;

static __device__ inline short f2bf(float x) {
  union { float f; unsigned u; } v; v.f = x;
  unsigned r = (v.u + 0x7FFFu + ((v.u >> 16) & 1u)) >> 16;  // RNE
  return (short)r;
}
static __device__ inline float bf2f(short u) {
  union { unsigned u; float f; } v;
  v.u = ((unsigned)(unsigned short)u) << 16;
  return v.f;
}
static __device__ inline unsigned cvt_pk_bf16(float lo, float hi) {
  unsigned d;
  asm("v_cvt_pk_bf16_f32 %0, %1, %2" : "=v"(d) : "v"(lo), "v"(hi));
  return d;
}

// ---------------- fused LN + QKV projections (MFMA), in-block W transpose, frag-major outputs ----------------
__global__ __launch_bounds__(256) void k_qkv(const float* __restrict__ x, const float* __restrict__ ln_w,
                                             const float* __restrict__ Wq, const float* __restrict__ Wk,
                                             const float* __restrict__ Wv, const float* __restrict__ gamma,
                                             short* __restrict__ Qf, short* __restrict__ Kf,
                                             short* __restrict__ Vf, float* __restrict__ aqg) {
  __shared__ short WtL[3 * 64 * 72];   // [w][f][e pad72] bf16 — per-block transposed weights
  __shared__ short QtL[2 * 32 * 72];   // [strip][s 32][f pad72]
  __shared__ short KtL[2 * 32 * 72];
  __shared__ float q2s[64];
  __shared__ float bks[64];            // exp2(cgk * k2[row])
  int blk = blockIdx.x;
  int bh = blk & 15, st = blk >> 4;
  int b = bh >> 3, h = bh & 7;
  int t = threadIdx.x, wid = t >> 6, lane = t & 63;
  int l31 = lane & 31, g = lane >> 5;
  int sh = wid >> 1, fh = wid & 1;
  int f = fh * 32 + l31;

  // ---- cooperative W transpose -> WtL (4x4 subtile per thread per matrix; weights L2-hot) ----
  {
    int e0 = (t >> 4) * 4, f0 = (t & 15) * 4;
    const float* srcs[3];
    srcs[0] = Wq + h * 4096; srcs[1] = Wk + h * 4096; srcs[2] = Wv + h * 4096;
#pragma unroll
    for (int wsel = 0; wsel < 3; ++wsel) {
      const float* src = srcs[wsel];
      f4v r0 = *(const f4v*)&src[(e0 + 0) * 64 + f0];
      f4v r1 = *(const f4v*)&src[(e0 + 1) * 64 + f0];
      f4v r2 = *(const f4v*)&src[(e0 + 2) * 64 + f0];
      f4v r3 = *(const f4v*)&src[(e0 + 3) * 64 + f0];
      short* dst = &WtL[wsel * 4608];
      s4v c0, c1, c2, c3;
      c0[0] = f2bf(r0.x); c0[1] = f2bf(r1.x); c0[2] = f2bf(r2.x); c0[3] = f2bf(r3.x);
      c1[0] = f2bf(r0.y); c1[1] = f2bf(r1.y); c1[2] = f2bf(r2.y); c1[3] = f2bf(r3.y);
      c2[0] = f2bf(r0.z); c2[1] = f2bf(r1.z); c2[2] = f2bf(r2.z); c2[3] = f2bf(r3.z);
      c3[0] = f2bf(r0.w); c3[1] = f2bf(r1.w); c3[2] = f2bf(r2.w); c3[3] = f2bf(r3.w);
      *(s4v*)&dst[(f0 + 0) * 72 + e0] = c0;
      *(s4v*)&dst[(f0 + 1) * 72 + e0] = c1;
      *(s4v*)&dst[(f0 + 2) * 72 + e0] = c2;
      *(s4v*)&dst[(f0 + 3) * 72 + e0] = c3;
    }
  }

  // ---- in-register LayerNorm over this lane's row ----
  int row = b * CS + st * 64 + sh * 32 + l31;
  f4v xv[8];
#pragma unroll
  for (int ks = 0; ks < 4; ++ks) {
    xv[2 * ks]     = *(const f4v*)&x[row * 64 + ks * 16 + g * 8];
    xv[2 * ks + 1] = *(const f4v*)&x[row * 64 + ks * 16 + g * 8 + 4];
  }
  float s = 0.f;
#pragma unroll
  for (int m = 0; m < 8; ++m) s += xv[m].x + xv[m].y + xv[m].z + xv[m].w;
  s += __shfl_xor(s, 32, 64);
  float mu = s * (1.f / 64.f);
  float vs = 0.f;
#pragma unroll
  for (int m = 0; m < 8; ++m) {
#pragma unroll
    for (int j = 0; j < 4; ++j) { float d = xv[m][j] - mu; vs += d * d; }
  }
  vs += __shfl_xor(vs, 32, 64);
  float rs = rsqrtf(vs * (1.f / 64.f) + EPS);
  bf8 af[4];
#pragma unroll
  for (int ks = 0; ks < 4; ++ks) {
    f4v lw0 = *(const f4v*)&ln_w[ks * 16 + g * 8];
    f4v lw1 = *(const f4v*)&ln_w[ks * 16 + g * 8 + 4];
#pragma unroll
    for (int j = 0; j < 4; ++j) {
      af[ks][j]     = f2bf((xv[2 * ks][j] - mu) * rs * lw0[j]);
      af[ks][j + 4] = f2bf((xv[2 * ks + 1][j] - mu) * rs * lw1[j]);
    }
  }
  float gh = gamma[h];
  float cgk = -gh * 0.125f * LOG2E;  // -gamma/8 in log2 domain
  __syncthreads();                   // WtL ready

  // ---- Q -> LDS tile ----
  f16v cq; for (int i = 0; i < 16; ++i) cq[i] = 0.f;
#pragma unroll
  for (int ks = 0; ks < 4; ++ks) {
    bf8 bw = *(const bf8*)&WtL[0 * 4608 + f * 72 + ks * 16 + g * 8];
    cq = __builtin_amdgcn_mfma_f32_32x32x16_bf16(af[ks], bw, cq, 0, 0, 0);
  }
#pragma unroll
  for (int r = 0; r < 16; ++r) {
    int rl = (r & 3) + 8 * (r >> 2) + 4 * g;
    QtL[(sh * 32 + rl) * 72 + f] = f2bf(cq[r]);
  }
  // ---- K -> LDS tile ----
  f16v ck; for (int i = 0; i < 16; ++i) ck[i] = 0.f;
#pragma unroll
  for (int ks = 0; ks < 4; ++ks) {
    bf8 bw = *(const bf8*)&WtL[1 * 4608 + f * 72 + ks * 16 + g * 8];
    ck = __builtin_amdgcn_mfma_f32_32x32x16_bf16(af[ks], bw, ck, 0, 0, 0);
  }
#pragma unroll
  for (int r = 0; r < 16; ++r) {
    int rl = (r & 3) + 8 * (r >> 2) + 4 * g;
    KtL[(sh * 32 + rl) * 72 + f] = f2bf(ck[r]);
  }
  // ---- V (stays in regs) ----
  f16v cv; for (int i = 0; i < 16; ++i) cv[i] = 0.f;
#pragma unroll
  for (int ks = 0; ks < 4; ++ks) {
    bf8 bw = *(const bf8*)&WtL[2 * 4608 + f * 72 + ks * 16 + g * 8];
    cv = __builtin_amdgcn_mfma_f32_32x32x16_bf16(af[ks], bw, cv, 0, 0, 0);
  }
  __syncthreads();

  // ---- cooperative q2/k2 (4 threads/row) + per-row bk = exp2(cgk*k2) ----
  {
    int rw = t >> 2, q4 = t & 3;
    float sq = 0.f, sk = 0.f;
#pragma unroll
    for (int m = 0; m < 2; ++m) {
      bf8 vq = *(bf8*)&QtL[rw * 72 + q4 * 16 + m * 8];
      bf8 vk = *(bf8*)&KtL[rw * 72 + q4 * 16 + m * 8];
#pragma unroll
      for (int j = 0; j < 8; ++j) {
        float xq = bf2f(vq[j]); sq += xq * xq;
        float xk = bf2f(vk[j]); sk += xk * xk;
      }
    }
    sq += __shfl_xor(sq, 1, 64); sq += __shfl_xor(sq, 2, 64);
    sk += __shfl_xor(sk, 1, 64); sk += __shfl_xor(sk, 2, 64);
    if (q4 == 0) {
      q2s[rw] = sq;
      bks[rw] = exp2f(cgk * sk);
    }
  }
  // ---- cooperative packed frag-major stores: Qf and Kf [bh][strip][ks][lane][8], 4x8B each ----
  {
    int ktloc = t >> 7, lm = (t >> 1) & 63, jh = t & 1;
#pragma unroll
    for (int ks = 0; ks < 4; ++ks) {
      int laddr = (ktloc * 32 + (lm & 31)) * 72 + ks * 16 + (lm >> 5) * 8 + jh * 4;
      int gaddr = ((bh * 64 + st * 2 + ktloc) * 4 + ks) * 512 + lm * 8 + jh * 4;
      *(s4v*)&Qf[gaddr] = *(s4v*)&QtL[laddr];
      *(s4v*)&Kf[gaddr] = *(s4v*)&KtL[laddr];
    }
  }
  __syncthreads();

  // ---- V' -> frag-major Vf[bh][kt][eh][ks2][lane][8], scaled by bks[row] ----
  int kt = st * 2 + sh;
#pragma unroll
  for (int m = 0; m < 4; ++m) {
    s4v pk;
#pragma unroll
    for (int c = 0; c < 4; ++c) {
      int rl = sh * 32 + c + 8 * m + 4 * g;
      pk[c] = f2bf(cv[m * 4 + c] * bks[rl]);
    }
    int addr = ((((bh * 64 + kt) * 2 + fh) * 2 + (m >> 1)) * 64 + (m & 1) * 32 + l31) * 8 + 4 * g;
    *(s4v*)&Vf[addr] = pk;
  }
  if (t < 64) {
    aqg[bh * CS + st * 64 + t] = exp2f(cgk * q2s[t]);
  }
}

// ---------------- fused causal RBF attention (MFMA, r10-proven single-strip, diag split out) ----------------
// Block = (bh, 32-row q-strip); 8 waves split the k range; no sync in main loop; LDS reduce at end.
// Register budget: ~64 arch + 48 acc = 112 <= 128 cap of (512,4) -> no spill (r11 lesson: unified file).
__global__ __launch_bounds__(512, 4) void k_attn(const short* __restrict__ Qf, const short* __restrict__ Kf,
                                                 const short* __restrict__ Vf, const float* __restrict__ aqg,
                                                 const float* __restrict__ gamma, short* __restrict__ attnB) {
  __shared__ float red4[4][64][37];
  int bid = blockIdx.x;
  int bh = ((bid & 7) << 1) | ((bid >> 3) & 1);  // bh pinned per XCD (L2 locality)
  int qt = 63 - (bid >> 4);                      // long q-strips dispatched first
  int b = bh >> 3, h = bh & 7;
  int t = threadIdx.x, w = t >> 6, lane = t & 63;
  int lam = lane & 31, g = lane >> 5;
  float cg = gamma[h] * 0.25f * LOG2E;           // +gamma/4 in log2 domain
  int L = qt + 1;
  int lo = (w * L) >> 3, hi = ((w + 1) * L) >> 3;
  int hiND = hi < qt ? hi : qt;                  // unmasked steps; only wave 7 owns kt==qt

  // Q B-frags for this strip: 4 coalesced 1KB loads from frag-major Qf
  bf8 qf[4];
#pragma unroll
  for (int ks = 0; ks < 4; ++ks) qf[ks] = *(const bf8*)&Qf[((bh * 64 + qt) * 4 + ks) * 512 + lane * 8];

  f16v oa0, oa1;
#pragma unroll
  for (int rr = 0; rr < 16; ++rr) { oa0[rr] = 0.f; oa1[rr] = 0.f; }

  const short* kfb = Kf + bh * 131072 + lane * 8;
  const short* vfb = Vf + bh * 131072 + lane * 8;

  // ---- unmasked main loop ----
  for (int kt = lo; kt < hiND; ++kt) {
    const short* kp = kfb + kt * 2048;
    bf8 ak0 = *(const bf8*)(kp);
    bf8 ak1 = *(const bf8*)(kp + 512);
    bf8 ak2 = *(const bf8*)(kp + 1024);
    bf8 ak3 = *(const bf8*)(kp + 1536);

    f16v ct;
#pragma unroll
    for (int rr = 0; rr < 16; ++rr) ct[rr] = 0.f;
    __builtin_amdgcn_s_setprio(1);
    ct = __builtin_amdgcn_mfma_f32_32x32x16_bf16(ak0, qf[0], ct, 0, 0, 0);
    ct = __builtin_amdgcn_mfma_f32_32x32x16_bf16(ak1, qf[1], ct, 0, 0, 0);
    ct = __builtin_amdgcn_mfma_f32_32x32x16_bf16(ak2, qf[2], ct, 0, 0, 0);
    ct = __builtin_amdgcn_mfma_f32_32x32x16_bf16(ak3, qf[3], ct, 0, 0, 0);
    __builtin_amdgcn_s_setprio(0);

    const short* vp = vfb + kt * 2048;
    bf8 av00 = *(const bf8*)(vp);
    bf8 av01 = *(const bf8*)(vp + 512);
    bf8 av10 = *(const bf8*)(vp + 1024);
    bf8 av11 = *(const bf8*)(vp + 1536);

    unsigned pkA[4], pkB[4];
#pragma unroll
    for (int m = 0; m < 4; ++m) {
      float e0 = exp2f(cg * ct[4 * m + 0]);
      float e1 = exp2f(cg * ct[4 * m + 1]);
      float e2 = exp2f(cg * ct[4 * m + 2]);
      float e3 = exp2f(cg * ct[4 * m + 3]);
      pkA[m] = cvt_pk_bf16(e0, e1);
      pkB[m] = cvt_pk_bf16(e2, e3);
    }
    __builtin_amdgcn_s_setprio(1);
#pragma unroll
    for (int ks2 = 0; ks2 < 2; ++ks2) {
      unsigned sendA = g ? pkA[2 * ks2] : pkA[2 * ks2 + 1];
      unsigned recvA = (unsigned)__shfl_xor((int)sendA, 32, 64);
      unsigned sendB = g ? pkB[2 * ks2] : pkB[2 * ks2 + 1];
      unsigned recvB = (unsigned)__shfl_xor((int)sendB, 32, 64);
      i4v wv;
      wv.x = g ? (int)recvA : (int)pkA[2 * ks2];
      wv.y = g ? (int)recvB : (int)pkB[2 * ks2];
      wv.z = g ? (int)pkA[2 * ks2 + 1] : (int)recvA;
      wv.w = g ? (int)pkB[2 * ks2 + 1] : (int)recvB;
      bf8 bs = *(bf8*)&wv;
      oa0 = __builtin_amdgcn_mfma_f32_32x32x16_bf16(ks2 ? av01 : av00, bs, oa0, 0, 0, 0);
      oa1 = __builtin_amdgcn_mfma_f32_32x32x16_bf16(ks2 ? av11 : av10, bs, oa1, 0, 0, 0);
    }
    __builtin_amdgcn_s_setprio(0);
  }

  // ---- diagonal tile (wave 7 only): same body with causal mask ----
  if (hi > hiND) {
    int kt = qt;
    const short* kp = kfb + kt * 2048;
    bf8 ak0 = *(const bf8*)(kp);
    bf8 ak1 = *(const bf8*)(kp + 512);
    bf8 ak2 = *(const bf8*)(kp + 1024);
    bf8 ak3 = *(const bf8*)(kp + 1536);

    f16v ct;
#pragma unroll
    for (int rr = 0; rr < 16; ++rr) ct[rr] = 0.f;
    ct = __builtin_amdgcn_mfma_f32_32x32x16_bf16(ak0, qf[0], ct, 0, 0, 0);
    ct = __builtin_amdgcn_mfma_f32_32x32x16_bf16(ak1, qf[1], ct, 0, 0, 0);
    ct = __builtin_amdgcn_mfma_f32_32x32x16_bf16(ak2, qf[2], ct, 0, 0, 0);
    ct = __builtin_amdgcn_mfma_f32_32x32x16_bf16(ak3, qf[3], ct, 0, 0, 0);

    const short* vp = vfb + kt * 2048;
    bf8 av00 = *(const bf8*)(vp);
    bf8 av01 = *(const bf8*)(vp + 512);
    bf8 av10 = *(const bf8*)(vp + 1024);
    bf8 av11 = *(const bf8*)(vp + 1536);

    unsigned pkA[4], pkB[4];
#pragma unroll
    for (int m = 0; m < 4; ++m) {
      float sv[4];
#pragma unroll
      for (int ii = 0; ii < 4; ++ii) {
        int kloc = ii + 8 * m + 4 * g;
        float ev = exp2f(cg * ct[4 * m + ii]);
        if (kloc > lam) ev = 0.f;
        sv[ii] = ev;
      }
      pkA[m] = cvt_pk_bf16(sv[0], sv[1]);
      pkB[m] = cvt_pk_bf16(sv[2], sv[3]);
    }
#pragma unroll
    for (int ks2 = 0; ks2 < 2; ++ks2) {
      unsigned sendA = g ? pkA[2 * ks2] : pkA[2 * ks2 + 1];
      unsigned recvA = (unsigned)__shfl_xor((int)sendA, 32, 64);
      unsigned sendB = g ? pkB[2 * ks2] : pkB[2 * ks2 + 1];
      unsigned recvB = (unsigned)__shfl_xor((int)sendB, 32, 64);
      i4v wv;
      wv.x = g ? (int)recvA : (int)pkA[2 * ks2];
      wv.y = g ? (int)recvB : (int)pkB[2 * ks2];
      wv.z = g ? (int)pkA[2 * ks2 + 1] : (int)recvA;
      wv.w = g ? (int)pkB[2 * ks2 + 1] : (int)recvB;
      bf8 bs = *(bf8*)&wv;
      oa0 = __builtin_amdgcn_mfma_f32_32x32x16_bf16(ks2 ? av01 : av00, bs, oa0, 0, 0, 0);
      oa1 = __builtin_amdgcn_mfma_f32_32x32x16_bf16(ks2 ? av11 : av10, bs, oa1, 0, 0, 0);
    }
  }

  // ---- epilogue: 8-way cross-wave reduce in LDS, apply aq, coalesced bf16 store ----
  if (w < 4) {
#pragma unroll
    for (int rr = 0; rr < 16; ++rr) {
      int e = (rr & 3) + 8 * (rr >> 2) + 4 * g;
      red4[w][e][lam] = oa0[rr];
      red4[w][e + 32][lam] = oa1[rr];
    }
  }
  __syncthreads();
  if (w >= 4) {
#pragma unroll
    for (int rr = 0; rr < 16; ++rr) {
      int e = (rr & 3) + 8 * (rr >> 2) + 4 * g;
      red4[w - 4][e][lam] += oa0[rr];
      red4[w - 4][e + 32][lam] += oa1[rr];
    }
  }
  __syncthreads();
  {
    int q = t >> 4, e0 = (t & 15) * 4;
    float aqv = aqg[bh * CS + qt * 32 + q];
    s4v ov;
#pragma unroll
    for (int jj = 0; jj < 4; ++jj) {
      float v = red4[0][e0 + jj][q] + red4[1][e0 + jj][q] + red4[2][e0 + jj][q] + red4[3][e0 + jj][q];
      ov[jj] = f2bf(v * aqv);
    }
    *(s4v*)&attnB[(b * CS + qt * 32 + q) * 512 + h * 64 + e0] = ov;
  }
}

// ---------------- output projection (MFMA, 256 blocks, direct f32 Wo with in-reg bf16 cast) ----------------
__global__ __launch_bounds__(256) void k_proj(const short* __restrict__ attnB, const float* __restrict__ Wo,
                                              float* __restrict__ out) {
  __shared__ float red[4][32][36];
  int blk = blockIdx.x, t = threadIdx.x;
  int rt = blk >> 1, fh2 = blk & 1;
  int r0 = rt * 32;
  int kw = t >> 6, lane = t & 63, l31 = lane & 31, g = lane >> 5;
  f16v c; for (int i = 0; i < 16; ++i) c[i] = 0.f;
  int arow = (r0 + l31) * 512;
  int fw = fh2 * 32 + l31;           // Wo row (output feature)
#pragma unroll
  for (int ks = 0; ks < 8; ++ks) {
    int k0 = kw * 128 + ks * 16 + g * 8;
    bf8 a = *(const bf8*)&attnB[arow + k0];
    f4v w0 = *(const f4v*)&Wo[fw * 512 + k0];
    f4v w1 = *(const f4v*)&Wo[fw * 512 + k0 + 4];
    i4v wp;
    wp.x = (int)cvt_pk_bf16(w0.x, w0.y);
    wp.y = (int)cvt_pk_bf16(w0.z, w0.w);
    wp.z = (int)cvt_pk_bf16(w1.x, w1.y);
    wp.w = (int)cvt_pk_bf16(w1.z, w1.w);
    bf8 bw = *(bf8*)&wp;
    c = __builtin_amdgcn_mfma_f32_32x32x16_bf16(a, bw, c, 0, 0, 0);
  }
#pragma unroll
  for (int rr = 0; rr < 16; ++rr) {
    int rw = (rr & 3) + 8 * (rr >> 2) + 4 * g;
    red[kw][rw][l31] = c[rr];
  }
  __syncthreads();
  {
    int rw = t >> 3, f4 = (t & 7) * 4;
    f4v sum;
#pragma unroll
    for (int j = 0; j < 4; ++j)
      sum[j] = red[0][rw][f4 + j] + red[1][rw][f4 + j] + red[2][rw][f4 + j] + red[3][rw][f4 + j];
    *(f4v*)&out[(r0 + rw) * 64 + fh2 * 32 + f4] = sum;
  }
}

extern "C" void kernel_launch(void* const* d_in, const int* in_sizes, int n_in,
                              void* d_out, int out_size, void* d_ws, size_t ws_size,
                              hipStream_t stream) {
  const float* x     = (const float*)d_in[0];
  const float* ln_w  = (const float*)d_in[1];
  const float* Wq    = (const float*)d_in[2];
  const float* Wk    = (const float*)d_in[3];
  const float* Wv    = (const float*)d_in[4];
  const float* Wo    = (const float*)d_in[5];
  const float* gamma = (const float*)d_in[6];
  float* out = (float*)d_out;

  char* w = (char*)d_ws;
  short* Qf    = (short*)w;                               // 4 MB frag-major Q
  short* Kf    = (short*)(w + 4194304);                   // 4 MB frag-major K
  short* Vf    = (short*)(w + 2 * 4194304);               // 4 MB frag-major V'
  float* aqg   = (float*)(w + 3 * 4194304);               // 128 KB
  short* attnB = (short*)(w + 3 * 4194304 + 131072);      // 4 MB

  hipLaunchKernelGGL(k_qkv,  dim3(512),  dim3(256), 0, stream, x, ln_w, Wq, Wk, Wv, gamma, Qf, Kf, Vf, aqg);
  hipLaunchKernelGGL(k_attn, dim3(1024), dim3(512), 0, stream, Qf, Kf, Vf, aqg, gamma, attnB);
  hipLaunchKernelGGL(k_proj, dim3(256),  dim3(256), 0, stream, attnB, Wo, out);
}

// Round 14
// 41.115 us; speedup vs baseline: 1.4909x; 1.0198x over previous
//
#include <hip/hip_runtime.h>
#include <math.h>

typedef __attribute__((ext_vector_type(8))) short bf8;    // 8 x bf16 (bit pattern)
typedef __attribute__((ext_vector_type(4))) short s4v;    // 4 x bf16 (8B store)
typedef __attribute__((ext_vector_type(16))) float f16v;  // MFMA 32x32 accum
typedef __attribute__((ext_vector_type(4))) float f4v;
typedef __attribute__((ext_vector_type(4))) int i4v;

constexpr int CS = 2048;
constexpr float EPS = 1e-5f;
constexpr float LOG2E = 1.44269504088896f;

static __device__ inline short f2bf(float x) {
  union { float f; unsigned u; } v; v.f = x;
  unsigned r = (v.u + 0x7FFFu + ((v.u >> 16) & 1u)) >> 16;  // RNE
  return (short)r;
}
static __device__ inline float bf2f(short u) {
  union { unsigned u; float f; } v;
  v.u = ((unsigned)(unsigned short)u) << 16;
  return v.f;
}
static __device__ inline unsigned cvt_pk_bf16(float lo, float hi) {
  unsigned d;
  asm("v_cvt_pk_bf16_f32 %0, %1, %2" : "=v"(d) : "v"(lo), "v"(hi));
  return d;
}

// ---------------- fused LN + QKV projections (MFMA), in-block W transpose, frag-major outputs ----------------
// Q is pre-scaled by cg = gamma/4*log2e (folds the score scaling out of k_attn's hot loop).
__global__ __launch_bounds__(256) void k_qkv(const float* __restrict__ x, const float* __restrict__ ln_w,
                                             const float* __restrict__ Wq, const float* __restrict__ Wk,
                                             const float* __restrict__ Wv, const float* __restrict__ gamma,
                                             short* __restrict__ Qf, short* __restrict__ Kf,
                                             short* __restrict__ Vf, float* __restrict__ aqg) {
  __shared__ short WtL[3 * 64 * 72];   // [w][f][e pad72] bf16 — per-block transposed weights
  __shared__ short QtL[2 * 32 * 72];   // [strip][s 32][f pad72]
  __shared__ short KtL[2 * 32 * 72];
  __shared__ float q2s[64];
  __shared__ float bks[64];            // exp2(cgk * k2[row])
  int blk = blockIdx.x;
  int bh = blk & 15, st = blk >> 4;
  int b = bh >> 3, h = bh & 7;
  int t = threadIdx.x, wid = t >> 6, lane = t & 63;
  int l31 = lane & 31, g = lane >> 5;
  int sh = wid >> 1, fh = wid & 1;
  int f = fh * 32 + l31;

  // ---- cooperative W transpose -> WtL (4x4 subtile per thread per matrix; weights L2-hot) ----
  {
    int e0 = (t >> 4) * 4, f0 = (t & 15) * 4;
    const float* srcs[3];
    srcs[0] = Wq + h * 4096; srcs[1] = Wk + h * 4096; srcs[2] = Wv + h * 4096;
#pragma unroll
    for (int wsel = 0; wsel < 3; ++wsel) {
      const float* src = srcs[wsel];
      f4v r0 = *(const f4v*)&src[(e0 + 0) * 64 + f0];
      f4v r1 = *(const f4v*)&src[(e0 + 1) * 64 + f0];
      f4v r2 = *(const f4v*)&src[(e0 + 2) * 64 + f0];
      f4v r3 = *(const f4v*)&src[(e0 + 3) * 64 + f0];
      short* dst = &WtL[wsel * 4608];
      s4v c0, c1, c2, c3;
      c0[0] = f2bf(r0.x); c0[1] = f2bf(r1.x); c0[2] = f2bf(r2.x); c0[3] = f2bf(r3.x);
      c1[0] = f2bf(r0.y); c1[1] = f2bf(r1.y); c1[2] = f2bf(r2.y); c1[3] = f2bf(r3.y);
      c2[0] = f2bf(r0.z); c2[1] = f2bf(r1.z); c2[2] = f2bf(r2.z); c2[3] = f2bf(r3.z);
      c3[0] = f2bf(r0.w); c3[1] = f2bf(r1.w); c3[2] = f2bf(r2.w); c3[3] = f2bf(r3.w);
      *(s4v*)&dst[(f0 + 0) * 72 + e0] = c0;
      *(s4v*)&dst[(f0 + 1) * 72 + e0] = c1;
      *(s4v*)&dst[(f0 + 2) * 72 + e0] = c2;
      *(s4v*)&dst[(f0 + 3) * 72 + e0] = c3;
    }
  }

  // ---- in-register LayerNorm over this lane's row ----
  int row = b * CS + st * 64 + sh * 32 + l31;
  f4v xv[8];
#pragma unroll
  for (int ks = 0; ks < 4; ++ks) {
    xv[2 * ks]     = *(const f4v*)&x[row * 64 + ks * 16 + g * 8];
    xv[2 * ks + 1] = *(const f4v*)&x[row * 64 + ks * 16 + g * 8 + 4];
  }
  float s = 0.f;
#pragma unroll
  for (int m = 0; m < 8; ++m) s += xv[m].x + xv[m].y + xv[m].z + xv[m].w;
  s += __shfl_xor(s, 32, 64);
  float mu = s * (1.f / 64.f);
  float vs = 0.f;
#pragma unroll
  for (int m = 0; m < 8; ++m) {
#pragma unroll
    for (int j = 0; j < 4; ++j) { float d = xv[m][j] - mu; vs += d * d; }
  }
  vs += __shfl_xor(vs, 32, 64);
  float rs = rsqrtf(vs * (1.f / 64.f) + EPS);
  bf8 af[4];
#pragma unroll
  for (int ks = 0; ks < 4; ++ks) {
    f4v lw0 = *(const f4v*)&ln_w[ks * 16 + g * 8];
    f4v lw1 = *(const f4v*)&ln_w[ks * 16 + g * 8 + 4];
#pragma unroll
    for (int j = 0; j < 4; ++j) {
      af[ks][j]     = f2bf((xv[2 * ks][j] - mu) * rs * lw0[j]);
      af[ks][j + 4] = f2bf((xv[2 * ks + 1][j] - mu) * rs * lw1[j]);
    }
  }
  float gh = gamma[h];
  float cgk = -gh * 0.125f * LOG2E;       // -gamma/8 in log2 domain
  float cgq = gh * 0.25f * LOG2E;         // folded into Q: scores = exp2(ct) directly
  float icgq2 = 1.f / (cgq * cgq);        // to recover true q2 from scaled Q
  __syncthreads();                        // WtL ready

  // ---- Q -> LDS tile (PRE-SCALED by cgq) ----
  f16v cq; for (int i = 0; i < 16; ++i) cq[i] = 0.f;
#pragma unroll
  for (int ks = 0; ks < 4; ++ks) {
    bf8 bw = *(const bf8*)&WtL[0 * 4608 + f * 72 + ks * 16 + g * 8];
    cq = __builtin_amdgcn_mfma_f32_32x32x16_bf16(af[ks], bw, cq, 0, 0, 0);
  }
#pragma unroll
  for (int r = 0; r < 16; ++r) {
    int rl = (r & 3) + 8 * (r >> 2) + 4 * g;
    QtL[(sh * 32 + rl) * 72 + f] = f2bf(cq[r] * cgq);
  }
  // ---- K -> LDS tile ----
  f16v ck; for (int i = 0; i < 16; ++i) ck[i] = 0.f;
#pragma unroll
  for (int ks = 0; ks < 4; ++ks) {
    bf8 bw = *(const bf8*)&WtL[1 * 4608 + f * 72 + ks * 16 + g * 8];
    ck = __builtin_amdgcn_mfma_f32_32x32x16_bf16(af[ks], bw, ck, 0, 0, 0);
  }
#pragma unroll
  for (int r = 0; r < 16; ++r) {
    int rl = (r & 3) + 8 * (r >> 2) + 4 * g;
    KtL[(sh * 32 + rl) * 72 + f] = f2bf(ck[r]);
  }
  // ---- V (stays in regs) ----
  f16v cv; for (int i = 0; i < 16; ++i) cv[i] = 0.f;
#pragma unroll
  for (int ks = 0; ks < 4; ++ks) {
    bf8 bw = *(const bf8*)&WtL[2 * 4608 + f * 72 + ks * 16 + g * 8];
    cv = __builtin_amdgcn_mfma_f32_32x32x16_bf16(af[ks], bw, cv, 0, 0, 0);
  }
  __syncthreads();

  // ---- cooperative q2/k2 (4 threads/row) + per-row bk = exp2(cgk*k2) ----
  // QtL is cgq-scaled: true q2 = sq * icgq2.
  {
    int rw = t >> 2, q4 = t & 3;
    float sq = 0.f, sk = 0.f;
#pragma unroll
    for (int m = 0; m < 2; ++m) {
      bf8 vq = *(bf8*)&QtL[rw * 72 + q4 * 16 + m * 8];
      bf8 vk = *(bf8*)&KtL[rw * 72 + q4 * 16 + m * 8];
#pragma unroll
      for (int j = 0; j < 8; ++j) {
        float xq = bf2f(vq[j]); sq += xq * xq;
        float xk = bf2f(vk[j]); sk += xk * xk;
      }
    }
    sq += __shfl_xor(sq, 1, 64); sq += __shfl_xor(sq, 2, 64);
    sk += __shfl_xor(sk, 1, 64); sk += __shfl_xor(sk, 2, 64);
    if (q4 == 0) {
      q2s[rw] = sq * icgq2;
      bks[rw] = exp2f(cgk * sk);
    }
  }
  // ---- cooperative packed frag-major stores: Qf and Kf [bh][strip][ks][lane][8], 4x8B each ----
  {
    int ktloc = t >> 7, lm = (t >> 1) & 63, jh = t & 1;
#pragma unroll
    for (int ks = 0; ks < 4; ++ks) {
      int laddr = (ktloc * 32 + (lm & 31)) * 72 + ks * 16 + (lm >> 5) * 8 + jh * 4;
      int gaddr = ((bh * 64 + st * 2 + ktloc) * 4 + ks) * 512 + lm * 8 + jh * 4;
      *(s4v*)&Qf[gaddr] = *(s4v*)&QtL[laddr];
      *(s4v*)&Kf[gaddr] = *(s4v*)&KtL[laddr];
    }
  }
  __syncthreads();

  // ---- V' -> frag-major Vf[bh][kt][eh][ks2][lane][8], scaled by bks[row] ----
  int kt = st * 2 + sh;
#pragma unroll
  for (int m = 0; m < 4; ++m) {
    s4v pk;
#pragma unroll
    for (int c = 0; c < 4; ++c) {
      int rl = sh * 32 + c + 8 * m + 4 * g;
      pk[c] = f2bf(cv[m * 4 + c] * bks[rl]);
    }
    int addr = ((((bh * 64 + kt) * 2 + fh) * 2 + (m >> 1)) * 64 + (m & 1) * 32 + l31) * 8 + 4 * g;
    *(s4v*)&Vf[addr] = pk;
  }
  if (t < 64) {
    aqg[bh * CS + st * 64 + t] = exp2f(cgk * q2s[t]);
  }
}

// ---------------- fused causal RBF attention (MFMA, single-strip, permlane exchange, pre-scaled Q) ----------------
// permlane32_swap(vdst=pk_even, vsrc=pk_odd): vdst.row1 <-> vsrc.row0.
// After: vdst = {pk_even.lower, pk_odd.lower} = B-frag word0; vsrc = {pk_even.upper, pk_odd.upper} = word2.
__global__ __launch_bounds__(512, 4) void k_attn(const short* __restrict__ Qf, const short* __restrict__ Kf,
                                                 const short* __restrict__ Vf, const float* __restrict__ aqg,
                                                 const float* __restrict__ gamma, short* __restrict__ attnB) {
  __shared__ float red4[4][64][37];
  int bid = blockIdx.x;
  int bh = ((bid & 7) << 1) | ((bid >> 3) & 1);  // bh pinned per XCD (L2 locality)
  int qt = 63 - (bid >> 4);                      // long q-strips dispatched first
  int b = bh >> 3, h = bh & 7;
  int t = threadIdx.x, w = t >> 6, lane = t & 63;
  int lam = lane & 31, g = lane >> 5;
  int L = qt + 1;
  int lo = (w * L) >> 3, hi = ((w + 1) * L) >> 3;
  int hiND = hi < qt ? hi : qt;                  // unmasked steps; only wave 7 owns kt==qt

  // Q B-frags (pre-scaled by cg in k_qkv): 4 coalesced 1KB loads
  bf8 qf[4];
#pragma unroll
  for (int ks = 0; ks < 4; ++ks) qf[ks] = *(const bf8*)&Qf[((bh * 64 + qt) * 4 + ks) * 512 + lane * 8];

  f16v oa0, oa1;
#pragma unroll
  for (int rr = 0; rr < 16; ++rr) { oa0[rr] = 0.f; oa1[rr] = 0.f; }

  const short* kfb = Kf + bh * 131072 + lane * 8;
  const short* vfb = Vf + bh * 131072 + lane * 8;

  // ---- unmasked main loop ----
  for (int kt = lo; kt < hiND; ++kt) {
    const short* kp = kfb + kt * 2048;
    bf8 ak0 = *(const bf8*)(kp);
    bf8 ak1 = *(const bf8*)(kp + 512);
    bf8 ak2 = *(const bf8*)(kp + 1024);
    bf8 ak3 = *(const bf8*)(kp + 1536);

    f16v ct;
#pragma unroll
    for (int rr = 0; rr < 16; ++rr) ct[rr] = 0.f;
    __builtin_amdgcn_s_setprio(1);
    ct = __builtin_amdgcn_mfma_f32_32x32x16_bf16(ak0, qf[0], ct, 0, 0, 0);
    ct = __builtin_amdgcn_mfma_f32_32x32x16_bf16(ak1, qf[1], ct, 0, 0, 0);
    ct = __builtin_amdgcn_mfma_f32_32x32x16_bf16(ak2, qf[2], ct, 0, 0, 0);
    ct = __builtin_amdgcn_mfma_f32_32x32x16_bf16(ak3, qf[3], ct, 0, 0, 0);
    __builtin_amdgcn_s_setprio(0);

    const short* vp = vfb + kt * 2048;
    bf8 av00 = *(const bf8*)(vp);
    bf8 av01 = *(const bf8*)(vp + 512);
    bf8 av10 = *(const bf8*)(vp + 1024);
    bf8 av11 = *(const bf8*)(vp + 1536);

    // exp (Q pre-scaled: no multiply) + pack
    unsigned pkA[4], pkB[4];
#pragma unroll
    for (int m = 0; m < 4; ++m) {
      float e0 = exp2f(ct[4 * m + 0]);
      float e1 = exp2f(ct[4 * m + 1]);
      float e2 = exp2f(ct[4 * m + 2]);
      float e3 = exp2f(ct[4 * m + 3]);
      pkA[m] = cvt_pk_bf16(e0, e1);
      pkB[m] = cvt_pk_bf16(e2, e3);
    }
    __builtin_amdgcn_s_setprio(1);
#pragma unroll
    for (int ks2 = 0; ks2 < 2; ++ks2) {
      unsigned a0 = pkA[2 * ks2], a1 = pkA[2 * ks2 + 1];
      unsigned b0 = pkB[2 * ks2], b1 = pkB[2 * ks2 + 1];
      asm("v_permlane32_swap_b32 %0, %1" : "+v"(a0), "+v"(a1));   // vdst=pk_even -> word0; vsrc=pk_odd -> word2
      asm("v_permlane32_swap_b32 %0, %1" : "+v"(b0), "+v"(b1));
      i4v wv;
      wv.x = (int)a0; wv.y = (int)b0; wv.z = (int)a1; wv.w = (int)b1;
      bf8 bs = *(bf8*)&wv;
      oa0 = __builtin_amdgcn_mfma_f32_32x32x16_bf16(ks2 ? av01 : av00, bs, oa0, 0, 0, 0);
      oa1 = __builtin_amdgcn_mfma_f32_32x32x16_bf16(ks2 ? av11 : av10, bs, oa1, 0, 0, 0);
    }
    __builtin_amdgcn_s_setprio(0);
  }

  // ---- diagonal tile (wave 7 only): same body with causal mask ----
  if (hi > hiND) {
    int kt = qt;
    const short* kp = kfb + kt * 2048;
    bf8 ak0 = *(const bf8*)(kp);
    bf8 ak1 = *(const bf8*)(kp + 512);
    bf8 ak2 = *(const bf8*)(kp + 1024);
    bf8 ak3 = *(const bf8*)(kp + 1536);

    f16v ct;
#pragma unroll
    for (int rr = 0; rr < 16; ++rr) ct[rr] = 0.f;
    ct = __builtin_amdgcn_mfma_f32_32x32x16_bf16(ak0, qf[0], ct, 0, 0, 0);
    ct = __builtin_amdgcn_mfma_f32_32x32x16_bf16(ak1, qf[1], ct, 0, 0, 0);
    ct = __builtin_amdgcn_mfma_f32_32x32x16_bf16(ak2, qf[2], ct, 0, 0, 0);
    ct = __builtin_amdgcn_mfma_f32_32x32x16_bf16(ak3, qf[3], ct, 0, 0, 0);

    const short* vp = vfb + kt * 2048;
    bf8 av00 = *(const bf8*)(vp);
    bf8 av01 = *(const bf8*)(vp + 512);
    bf8 av10 = *(const bf8*)(vp + 1024);
    bf8 av11 = *(const bf8*)(vp + 1536);

    unsigned pkA[4], pkB[4];
#pragma unroll
    for (int m = 0; m < 4; ++m) {
      float sv[4];
#pragma unroll
      for (int ii = 0; ii < 4; ++ii) {
        int kloc = ii + 8 * m + 4 * g;
        float ev = exp2f(ct[4 * m + ii]);
        if (kloc > lam) ev = 0.f;
        sv[ii] = ev;
      }
      pkA[m] = cvt_pk_bf16(sv[0], sv[1]);
      pkB[m] = cvt_pk_bf16(sv[2], sv[3]);
    }
#pragma unroll
    for (int ks2 = 0; ks2 < 2; ++ks2) {
      unsigned a0 = pkA[2 * ks2], a1 = pkA[2 * ks2 + 1];
      unsigned b0 = pkB[2 * ks2], b1 = pkB[2 * ks2 + 1];
      asm("v_permlane32_swap_b32 %0, %1" : "+v"(a0), "+v"(a1));
      asm("v_permlane32_swap_b32 %0, %1" : "+v"(b0), "+v"(b1));
      i4v wv;
      wv.x = (int)a0; wv.y = (int)b0; wv.z = (int)a1; wv.w = (int)b1;
      bf8 bs = *(bf8*)&wv;
      oa0 = __builtin_amdgcn_mfma_f32_32x32x16_bf16(ks2 ? av01 : av00, bs, oa0, 0, 0, 0);
      oa1 = __builtin_amdgcn_mfma_f32_32x32x16_bf16(ks2 ? av11 : av10, bs, oa1, 0, 0, 0);
    }
  }

  // ---- epilogue: 8-way cross-wave reduce in LDS, apply aq, coalesced bf16 store ----
  if (w < 4) {
#pragma unroll
    for (int rr = 0; rr < 16; ++rr) {
      int e = (rr & 3) + 8 * (rr >> 2) + 4 * g;
      red4[w][e][lam] = oa0[rr];
      red4[w][e + 32][lam] = oa1[rr];
    }
  }
  __syncthreads();
  if (w >= 4) {
#pragma unroll
    for (int rr = 0; rr < 16; ++rr) {
      int e = (rr & 3) + 8 * (rr >> 2) + 4 * g;
      red4[w - 4][e][lam] += oa0[rr];
      red4[w - 4][e + 32][lam] += oa1[rr];
    }
  }
  __syncthreads();
  {
    int q = t >> 4, e0 = (t & 15) * 4;
    float aqv = aqg[bh * CS + qt * 32 + q];
    s4v ov;
#pragma unroll
    for (int jj = 0; jj < 4; ++jj) {
      float v = red4[0][e0 + jj][q] + red4[1][e0 + jj][q] + red4[2][e0 + jj][q] + red4[3][e0 + jj][q];
      ov[jj] = f2bf(v * aqv);
    }
    *(s4v*)&attnB[(b * CS + qt * 32 + q) * 512 + h * 64 + e0] = ov;
  }
}

// ---------------- output projection (MFMA, 256 blocks, direct f32 Wo with in-reg bf16 cast) ----------------
__global__ __launch_bounds__(256) void k_proj(const short* __restrict__ attnB, const float* __restrict__ Wo,
                                              float* __restrict__ out) {
  __shared__ float red[4][32][36];
  int blk = blockIdx.x, t = threadIdx.x;
  int rt = blk >> 1, fh2 = blk & 1;
  int r0 = rt * 32;
  int kw = t >> 6, lane = t & 63, l31 = lane & 31, g = lane >> 5;
  f16v c; for (int i = 0; i < 16; ++i) c[i] = 0.f;
  int arow = (r0 + l31) * 512;
  int fw = fh2 * 32 + l31;           // Wo row (output feature)
#pragma unroll
  for (int ks = 0; ks < 8; ++ks) {
    int k0 = kw * 128 + ks * 16 + g * 8;
    bf8 a = *(const bf8*)&attnB[arow + k0];
    f4v w0 = *(const f4v*)&Wo[fw * 512 + k0];
    f4v w1 = *(const f4v*)&Wo[fw * 512 + k0 + 4];
    i4v wp;
    wp.x = (int)cvt_pk_bf16(w0.x, w0.y);
    wp.y = (int)cvt_pk_bf16(w0.z, w0.w);
    wp.z = (int)cvt_pk_bf16(w1.x, w1.y);
    wp.w = (int)cvt_pk_bf16(w1.z, w1.w);
    bf8 bw = *(bf8*)&wp;
    c = __builtin_amdgcn_mfma_f32_32x32x16_bf16(a, bw, c, 0, 0, 0);
  }
#pragma unroll
  for (int rr = 0; rr < 16; ++rr) {
    int rw = (rr & 3) + 8 * (rr >> 2) + 4 * g;
    red[kw][rw][l31] = c[rr];
  }
  __syncthreads();
  {
    int rw = t >> 3, f4 = (t & 7) * 4;
    f4v sum;
#pragma unroll
    for (int j = 0; j < 4; ++j)
      sum[j] = red[0][rw][f4 + j] + red[1][rw][f4 + j] + red[2][rw][f4 + j] + red[3][rw][f4 + j];
    *(f4v*)&out[(r0 + rw) * 64 + fh2 * 32 + f4] = sum;
  }
}

extern "C" void kernel_launch(void* const* d_in, const int* in_sizes, int n_in,
                              void* d_out, int out_size, void* d_ws, size_t ws_size,
                              hipStream_t stream) {
  const float* x     = (const float*)d_in[0];
  const float* ln_w  = (const float*)d_in[1];
  const float* Wq    = (const float*)d_in[2];
  const float* Wk    = (const float*)d_in[3];
  const float* Wv    = (const float*)d_in[4];
  const float* Wo    = (const float*)d_in[5];
  const float* gamma = (const float*)d_in[6];
  float* out = (float*)d_out;

  char* w = (char*)d_ws;
  short* Qf    = (short*)w;                               // 4 MB frag-major Q (pre-scaled)
  short* Kf    = (short*)(w + 4194304);                   // 4 MB frag-major K
  short* Vf    = (short*)(w + 2 * 4194304);               // 4 MB frag-major V'
  float* aqg   = (float*)(w + 3 * 4194304);               // 128 KB
  short* attnB = (short*)(w + 3 * 4194304 + 131072);      // 4 MB

  hipLaunchKernelGGL(k_qkv,  dim3(512),  dim3(256), 0, stream, x, ln_w, Wq, Wk, Wv, gamma, Qf, Kf, Vf, aqg);
  hipLaunchKernelGGL(k_attn, dim3(1024), dim3(512), 0, stream, Qf, Kf, Vf, aqg, gamma, attnB);
  hipLaunchKernelGGL(k_proj, dim3(256),  dim3(256), 0, stream, attnB, Wo, out);
}

// Round 15
// 40.612 us; speedup vs baseline: 1.5094x; 1.0124x over previous
//
#include <hip/hip_runtime.h>
#include <math.h>

typedef __attribute__((ext_vector_type(8))) short bf8;    // 8 x bf16 (bit pattern)
typedef __attribute__((ext_vector_type(4))) short s4v;    // 4 x bf16 (8B store)
typedef __attribute__((ext_vector_type(16))) float f16v;  // MFMA 32x32 accum
typedef __attribute__((ext_vector_type(4))) float f4v;
typedef __attribute__((ext_vector_type(4))) int i4v;

constexpr int CS = 2048;
constexpr float EPS = 1e-5f;
constexpr float LOG2E = 1.44269504088896f;

static __device__ inline short f2bf(float x) {
  union { float f; unsigned u; } v; v.f = x;
  unsigned r = (v.u + 0x7FFFu + ((v.u >> 16) & 1u)) >> 16;  // RNE
  return (short)r;
}
static __device__ inline float bf2f(short u) {
  union { unsigned u; float f; } v;
  v.u = ((unsigned)(unsigned short)u) << 16;
  return v.f;
}
static __device__ inline unsigned cvt_pk_bf16(float lo, float hi) {
  unsigned d;
  asm("v_cvt_pk_bf16_f32 %0, %1, %2" : "=v"(d) : "v"(lo), "v"(hi));
  return d;
}

// ---------------- fused LN + QKV projections (MFMA), in-block W transpose, frag-major outputs ----------------
// Q is pre-scaled by cg = gamma/4*log2e (folds the score scaling out of k_attn's hot loop).
__global__ __launch_bounds__(256) void k_qkv(const float* __restrict__ x, const float* __restrict__ ln_w,
                                             const float* __restrict__ Wq, const float* __restrict__ Wk,
                                             const float* __restrict__ Wv, const float* __restrict__ gamma,
                                             short* __restrict__ Qf, short* __restrict__ Kf,
                                             short* __restrict__ Vf, float* __restrict__ aqg) {
  __shared__ short WtL[3 * 64 * 72];   // [w][f][e pad72] bf16 — per-block transposed weights
  __shared__ short QtL[2 * 32 * 72];   // [strip][s 32][f pad72]
  __shared__ short KtL[2 * 32 * 72];
  __shared__ float q2s[64];
  __shared__ float bks[64];            // exp2(cgk * k2[row])
  int blk = blockIdx.x;
  int bh = blk & 15, st = blk >> 4;
  int b = bh >> 3, h = bh & 7;
  int t = threadIdx.x, wid = t >> 6, lane = t & 63;
  int l31 = lane & 31, g = lane >> 5;
  int sh = wid >> 1, fh = wid & 1;
  int f = fh * 32 + l31;

  // ---- cooperative W transpose -> WtL (4x4 subtile per thread per matrix; weights L2-hot) ----
  {
    int e0 = (t >> 4) * 4, f0 = (t & 15) * 4;
    const float* srcs[3];
    srcs[0] = Wq + h * 4096; srcs[1] = Wk + h * 4096; srcs[2] = Wv + h * 4096;
#pragma unroll
    for (int wsel = 0; wsel < 3; ++wsel) {
      const float* src = srcs[wsel];
      f4v r0 = *(const f4v*)&src[(e0 + 0) * 64 + f0];
      f4v r1 = *(const f4v*)&src[(e0 + 1) * 64 + f0];
      f4v r2 = *(const f4v*)&src[(e0 + 2) * 64 + f0];
      f4v r3 = *(const f4v*)&src[(e0 + 3) * 64 + f0];
      short* dst = &WtL[wsel * 4608];
      s4v c0, c1, c2, c3;
      c0[0] = f2bf(r0.x); c0[1] = f2bf(r1.x); c0[2] = f2bf(r2.x); c0[3] = f2bf(r3.x);
      c1[0] = f2bf(r0.y); c1[1] = f2bf(r1.y); c1[2] = f2bf(r2.y); c1[3] = f2bf(r3.y);
      c2[0] = f2bf(r0.z); c2[1] = f2bf(r1.z); c2[2] = f2bf(r2.z); c2[3] = f2bf(r3.z);
      c3[0] = f2bf(r0.w); c3[1] = f2bf(r1.w); c3[2] = f2bf(r2.w); c3[3] = f2bf(r3.w);
      *(s4v*)&dst[(f0 + 0) * 72 + e0] = c0;
      *(s4v*)&dst[(f0 + 1) * 72 + e0] = c1;
      *(s4v*)&dst[(f0 + 2) * 72 + e0] = c2;
      *(s4v*)&dst[(f0 + 3) * 72 + e0] = c3;
    }
  }

  // ---- in-register LayerNorm over this lane's row ----
  int row = b * CS + st * 64 + sh * 32 + l31;
  f4v xv[8];
#pragma unroll
  for (int ks = 0; ks < 4; ++ks) {
    xv[2 * ks]     = *(const f4v*)&x[row * 64 + ks * 16 + g * 8];
    xv[2 * ks + 1] = *(const f4v*)&x[row * 64 + ks * 16 + g * 8 + 4];
  }
  float s = 0.f;
#pragma unroll
  for (int m = 0; m < 8; ++m) s += xv[m].x + xv[m].y + xv[m].z + xv[m].w;
  s += __shfl_xor(s, 32, 64);
  float mu = s * (1.f / 64.f);
  float vs = 0.f;
#pragma unroll
  for (int m = 0; m < 8; ++m) {
#pragma unroll
    for (int j = 0; j < 4; ++j) { float d = xv[m][j] - mu; vs += d * d; }
  }
  vs += __shfl_xor(vs, 32, 64);
  float rs = rsqrtf(vs * (1.f / 64.f) + EPS);
  bf8 af[4];
#pragma unroll
  for (int ks = 0; ks < 4; ++ks) {
    f4v lw0 = *(const f4v*)&ln_w[ks * 16 + g * 8];
    f4v lw1 = *(const f4v*)&ln_w[ks * 16 + g * 8 + 4];
#pragma unroll
    for (int j = 0; j < 4; ++j) {
      af[ks][j]     = f2bf((xv[2 * ks][j] - mu) * rs * lw0[j]);
      af[ks][j + 4] = f2bf((xv[2 * ks + 1][j] - mu) * rs * lw1[j]);
    }
  }
  float gh = gamma[h];
  float cgk = -gh * 0.125f * LOG2E;       // -gamma/8 in log2 domain
  float cgq = gh * 0.25f * LOG2E;         // folded into Q: scores = exp2(ct) directly
  float icgq2 = 1.f / (cgq * cgq);        // to recover true q2 from scaled Q
  __syncthreads();                        // WtL ready

  // ---- Q -> LDS tile (PRE-SCALED by cgq) ----
  f16v cq; for (int i = 0; i < 16; ++i) cq[i] = 0.f;
#pragma unroll
  for (int ks = 0; ks < 4; ++ks) {
    bf8 bw = *(const bf8*)&WtL[0 * 4608 + f * 72 + ks * 16 + g * 8];
    cq = __builtin_amdgcn_mfma_f32_32x32x16_bf16(af[ks], bw, cq, 0, 0, 0);
  }
#pragma unroll
  for (int r = 0; r < 16; ++r) {
    int rl = (r & 3) + 8 * (r >> 2) + 4 * g;
    QtL[(sh * 32 + rl) * 72 + f] = f2bf(cq[r] * cgq);
  }
  // ---- K -> LDS tile ----
  f16v ck; for (int i = 0; i < 16; ++i) ck[i] = 0.f;
#pragma unroll
  for (int ks = 0; ks < 4; ++ks) {
    bf8 bw = *(const bf8*)&WtL[1 * 4608 + f * 72 + ks * 16 + g * 8];
    ck = __builtin_amdgcn_mfma_f32_32x32x16_bf16(af[ks], bw, ck, 0, 0, 0);
  }
#pragma unroll
  for (int r = 0; r < 16; ++r) {
    int rl = (r & 3) + 8 * (r >> 2) + 4 * g;
    KtL[(sh * 32 + rl) * 72 + f] = f2bf(ck[r]);
  }
  // ---- V (stays in regs) ----
  f16v cv; for (int i = 0; i < 16; ++i) cv[i] = 0.f;
#pragma unroll
  for (int ks = 0; ks < 4; ++ks) {
    bf8 bw = *(const bf8*)&WtL[2 * 4608 + f * 72 + ks * 16 + g * 8];
    cv = __builtin_amdgcn_mfma_f32_32x32x16_bf16(af[ks], bw, cv, 0, 0, 0);
  }
  __syncthreads();

  // ---- cooperative q2/k2 (4 threads/row) + per-row bk = exp2(cgk*k2) ----
  // QtL is cgq-scaled: true q2 = sq * icgq2.
  {
    int rw = t >> 2, q4 = t & 3;
    float sq = 0.f, sk = 0.f;
#pragma unroll
    for (int m = 0; m < 2; ++m) {
      bf8 vq = *(bf8*)&QtL[rw * 72 + q4 * 16 + m * 8];
      bf8 vk = *(bf8*)&KtL[rw * 72 + q4 * 16 + m * 8];
#pragma unroll
      for (int j = 0; j < 8; ++j) {
        float xq = bf2f(vq[j]); sq += xq * xq;
        float xk = bf2f(vk[j]); sk += xk * xk;
      }
    }
    sq += __shfl_xor(sq, 1, 64); sq += __shfl_xor(sq, 2, 64);
    sk += __shfl_xor(sk, 1, 64); sk += __shfl_xor(sk, 2, 64);
    if (q4 == 0) {
      q2s[rw] = sq * icgq2;
      bks[rw] = exp2f(cgk * sk);
    }
  }
  // ---- cooperative packed frag-major stores: Qf and Kf [bh][strip][ks][lane][8], 4x8B each ----
  {
    int ktloc = t >> 7, lm = (t >> 1) & 63, jh = t & 1;
#pragma unroll
    for (int ks = 0; ks < 4; ++ks) {
      int laddr = (ktloc * 32 + (lm & 31)) * 72 + ks * 16 + (lm >> 5) * 8 + jh * 4;
      int gaddr = ((bh * 64 + st * 2 + ktloc) * 4 + ks) * 512 + lm * 8 + jh * 4;
      *(s4v*)&Qf[gaddr] = *(s4v*)&QtL[laddr];
      *(s4v*)&Kf[gaddr] = *(s4v*)&KtL[laddr];
    }
  }
  __syncthreads();

  // ---- V' -> frag-major Vf[bh][kt][eh][ks2][lane][8], scaled by bks[row] ----
  int kt = st * 2 + sh;
#pragma unroll
  for (int m = 0; m < 4; ++m) {
    s4v pk;
#pragma unroll
    for (int c = 0; c < 4; ++c) {
      int rl = sh * 32 + c + 8 * m + 4 * g;
      pk[c] = f2bf(cv[m * 4 + c] * bks[rl]);
    }
    int addr = ((((bh * 64 + kt) * 2 + fh) * 2 + (m >> 1)) * 64 + (m & 1) * 32 + l31) * 8 + 4 * g;
    *(s4v*)&Vf[addr] = pk;
  }
  if (t < 64) {
    aqg[bh * CS + st * 64 + t] = exp2f(cgk * q2s[t]);
  }
}

// ---------------- fused causal RBF attention (MFMA, single-strip, permlane exchange, pre-scaled Q) ----------------
// All 8 frag loads issue at loop top (one latency window); unroll-2 lets the scheduler hoist the
// next iteration's independent loads under this iteration's MFMA/exp chain.
__global__ __launch_bounds__(512, 4) void k_attn(const short* __restrict__ Qf, const short* __restrict__ Kf,
                                                 const short* __restrict__ Vf, const float* __restrict__ aqg,
                                                 const float* __restrict__ gamma, short* __restrict__ attnB) {
  __shared__ float red4[4][64][37];
  int bid = blockIdx.x;
  int bh = ((bid & 7) << 1) | ((bid >> 3) & 1);  // bh pinned per XCD (L2 locality)
  int qt = 63 - (bid >> 4);                      // long q-strips dispatched first
  int b = bh >> 3, h = bh & 7;
  int t = threadIdx.x, w = t >> 6, lane = t & 63;
  int lam = lane & 31, g = lane >> 5;
  int L = qt + 1;
  int lo = (w * L) >> 3, hi = ((w + 1) * L) >> 3;
  int hiND = hi < qt ? hi : qt;                  // unmasked steps; only wave 7 owns kt==qt

  // Q B-frags (pre-scaled by cg in k_qkv): 4 coalesced 1KB loads
  bf8 qf[4];
#pragma unroll
  for (int ks = 0; ks < 4; ++ks) qf[ks] = *(const bf8*)&Qf[((bh * 64 + qt) * 4 + ks) * 512 + lane * 8];

  f16v oa0, oa1;
#pragma unroll
  for (int rr = 0; rr < 16; ++rr) { oa0[rr] = 0.f; oa1[rr] = 0.f; }

  const short* kfb = Kf + bh * 131072 + lane * 8;
  const short* vfb = Vf + bh * 131072 + lane * 8;

  // ---- unmasked main loop ----
#pragma unroll 2
  for (int kt = lo; kt < hiND; ++kt) {
    // all 8 coalesced frag loads issued together: one latency window per step
    const short* kp = kfb + kt * 2048;
    const short* vp = vfb + kt * 2048;
    bf8 ak0 = *(const bf8*)(kp);
    bf8 ak1 = *(const bf8*)(kp + 512);
    bf8 ak2 = *(const bf8*)(kp + 1024);
    bf8 ak3 = *(const bf8*)(kp + 1536);
    bf8 av00 = *(const bf8*)(vp);
    bf8 av01 = *(const bf8*)(vp + 512);
    bf8 av10 = *(const bf8*)(vp + 1024);
    bf8 av11 = *(const bf8*)(vp + 1536);

    f16v ct;
#pragma unroll
    for (int rr = 0; rr < 16; ++rr) ct[rr] = 0.f;
    __builtin_amdgcn_s_setprio(1);
    ct = __builtin_amdgcn_mfma_f32_32x32x16_bf16(ak0, qf[0], ct, 0, 0, 0);
    ct = __builtin_amdgcn_mfma_f32_32x32x16_bf16(ak1, qf[1], ct, 0, 0, 0);
    ct = __builtin_amdgcn_mfma_f32_32x32x16_bf16(ak2, qf[2], ct, 0, 0, 0);
    ct = __builtin_amdgcn_mfma_f32_32x32x16_bf16(ak3, qf[3], ct, 0, 0, 0);
    __builtin_amdgcn_s_setprio(0);

    // exp (Q pre-scaled: no multiply) + pack
    unsigned pkA[4], pkB[4];
#pragma unroll
    for (int m = 0; m < 4; ++m) {
      float e0 = exp2f(ct[4 * m + 0]);
      float e1 = exp2f(ct[4 * m + 1]);
      float e2 = exp2f(ct[4 * m + 2]);
      float e3 = exp2f(ct[4 * m + 3]);
      pkA[m] = cvt_pk_bf16(e0, e1);
      pkB[m] = cvt_pk_bf16(e2, e3);
    }
    __builtin_amdgcn_s_setprio(1);
#pragma unroll
    for (int ks2 = 0; ks2 < 2; ++ks2) {
      unsigned a0 = pkA[2 * ks2], a1 = pkA[2 * ks2 + 1];
      unsigned b0 = pkB[2 * ks2], b1 = pkB[2 * ks2 + 1];
      asm("v_permlane32_swap_b32 %0, %1" : "+v"(a0), "+v"(a1));   // vdst=pk_even -> word0; vsrc=pk_odd -> word2
      asm("v_permlane32_swap_b32 %0, %1" : "+v"(b0), "+v"(b1));
      i4v wv;
      wv.x = (int)a0; wv.y = (int)b0; wv.z = (int)a1; wv.w = (int)b1;
      bf8 bs = *(bf8*)&wv;
      oa0 = __builtin_amdgcn_mfma_f32_32x32x16_bf16(ks2 ? av01 : av00, bs, oa0, 0, 0, 0);
      oa1 = __builtin_amdgcn_mfma_f32_32x32x16_bf16(ks2 ? av11 : av10, bs, oa1, 0, 0, 0);
    }
    __builtin_amdgcn_s_setprio(0);
  }

  // ---- diagonal tile (wave 7 only): same body with causal mask ----
  if (hi > hiND) {
    int kt = qt;
    const short* kp = kfb + kt * 2048;
    const short* vp = vfb + kt * 2048;
    bf8 ak0 = *(const bf8*)(kp);
    bf8 ak1 = *(const bf8*)(kp + 512);
    bf8 ak2 = *(const bf8*)(kp + 1024);
    bf8 ak3 = *(const bf8*)(kp + 1536);
    bf8 av00 = *(const bf8*)(vp);
    bf8 av01 = *(const bf8*)(vp + 512);
    bf8 av10 = *(const bf8*)(vp + 1024);
    bf8 av11 = *(const bf8*)(vp + 1536);

    f16v ct;
#pragma unroll
    for (int rr = 0; rr < 16; ++rr) ct[rr] = 0.f;
    ct = __builtin_amdgcn_mfma_f32_32x32x16_bf16(ak0, qf[0], ct, 0, 0, 0);
    ct = __builtin_amdgcn_mfma_f32_32x32x16_bf16(ak1, qf[1], ct, 0, 0, 0);
    ct = __builtin_amdgcn_mfma_f32_32x32x16_bf16(ak2, qf[2], ct, 0, 0, 0);
    ct = __builtin_amdgcn_mfma_f32_32x32x16_bf16(ak3, qf[3], ct, 0, 0, 0);

    unsigned pkA[4], pkB[4];
#pragma unroll
    for (int m = 0; m < 4; ++m) {
      float sv[4];
#pragma unroll
      for (int ii = 0; ii < 4; ++ii) {
        int kloc = ii + 8 * m + 4 * g;
        float ev = exp2f(ct[4 * m + ii]);
        if (kloc > lam) ev = 0.f;
        sv[ii] = ev;
      }
      pkA[m] = cvt_pk_bf16(sv[0], sv[1]);
      pkB[m] = cvt_pk_bf16(sv[2], sv[3]);
    }
#pragma unroll
    for (int ks2 = 0; ks2 < 2; ++ks2) {
      unsigned a0 = pkA[2 * ks2], a1 = pkA[2 * ks2 + 1];
      unsigned b0 = pkB[2 * ks2], b1 = pkB[2 * ks2 + 1];
      asm("v_permlane32_swap_b32 %0, %1" : "+v"(a0), "+v"(a1));
      asm("v_permlane32_swap_b32 %0, %1" : "+v"(b0), "+v"(b1));
      i4v wv;
      wv.x = (int)a0; wv.y = (int)b0; wv.z = (int)a1; wv.w = (int)b1;
      bf8 bs = *(bf8*)&wv;
      oa0 = __builtin_amdgcn_mfma_f32_32x32x16_bf16(ks2 ? av01 : av00, bs, oa0, 0, 0, 0);
      oa1 = __builtin_amdgcn_mfma_f32_32x32x16_bf16(ks2 ? av11 : av10, bs, oa1, 0, 0, 0);
    }
  }

  // ---- epilogue: 8-way cross-wave reduce in LDS, apply aq, coalesced bf16 store ----
  if (w < 4) {
#pragma unroll
    for (int rr = 0; rr < 16; ++rr) {
      int e = (rr & 3) + 8 * (rr >> 2) + 4 * g;
      red4[w][e][lam] = oa0[rr];
      red4[w][e + 32][lam] = oa1[rr];
    }
  }
  __syncthreads();
  if (w >= 4) {
#pragma unroll
    for (int rr = 0; rr < 16; ++rr) {
      int e = (rr & 3) + 8 * (rr >> 2) + 4 * g;
      red4[w - 4][e][lam] += oa0[rr];
      red4[w - 4][e + 32][lam] += oa1[rr];
    }
  }
  __syncthreads();
  {
    int q = t >> 4, e0 = (t & 15) * 4;
    float aqv = aqg[bh * CS + qt * 32 + q];
    s4v ov;
#pragma unroll
    for (int jj = 0; jj < 4; ++jj) {
      float v = red4[0][e0 + jj][q] + red4[1][e0 + jj][q] + red4[2][e0 + jj][q] + red4[3][e0 + jj][q];
      ov[jj] = f2bf(v * aqv);
    }
    *(s4v*)&attnB[(b * CS + qt * 32 + q) * 512 + h * 64 + e0] = ov;
  }
}

// ---------------- output projection (MFMA, 256 blocks, direct f32 Wo with in-reg bf16 cast) ----------------
__global__ __launch_bounds__(256) void k_proj(const short* __restrict__ attnB, const float* __restrict__ Wo,
                                              float* __restrict__ out) {
  __shared__ float red[4][32][36];
  int blk = blockIdx.x, t = threadIdx.x;
  int rt = blk >> 1, fh2 = blk & 1;
  int r0 = rt * 32;
  int kw = t >> 6, lane = t & 63, l31 = lane & 31, g = lane >> 5;
  f16v c; for (int i = 0; i < 16; ++i) c[i] = 0.f;
  int arow = (r0 + l31) * 512;
  int fw = fh2 * 32 + l31;           // Wo row (output feature)
#pragma unroll
  for (int ks = 0; ks < 8; ++ks) {
    int k0 = kw * 128 + ks * 16 + g * 8;
    bf8 a = *(const bf8*)&attnB[arow + k0];
    f4v w0 = *(const f4v*)&Wo[fw * 512 + k0];
    f4v w1 = *(const f4v*)&Wo[fw * 512 + k0 + 4];
    i4v wp;
    wp.x = (int)cvt_pk_bf16(w0.x, w0.y);
    wp.y = (int)cvt_pk_bf16(w0.z, w0.w);
    wp.z = (int)cvt_pk_bf16(w1.x, w1.y);
    wp.w = (int)cvt_pk_bf16(w1.z, w1.w);
    bf8 bw = *(bf8*)&wp;
    c = __builtin_amdgcn_mfma_f32_32x32x16_bf16(a, bw, c, 0, 0, 0);
  }
#pragma unroll
  for (int rr = 0; rr < 16; ++rr) {
    int rw = (rr & 3) + 8 * (rr >> 2) + 4 * g;
    red[kw][rw][l31] = c[rr];
  }
  __syncthreads();
  {
    int rw = t >> 3, f4 = (t & 7) * 4;
    f4v sum;
#pragma unroll
    for (int j = 0; j < 4; ++j)
      sum[j] = red[0][rw][f4 + j] + red[1][rw][f4 + j] + red[2][rw][f4 + j] + red[3][rw][f4 + j];
    *(f4v*)&out[(r0 + rw) * 64 + fh2 * 32 + f4] = sum;
  }
}

extern "C" void kernel_launch(void* const* d_in, const int* in_sizes, int n_in,
                              void* d_out, int out_size, void* d_ws, size_t ws_size,
                              hipStream_t stream) {
  const float* x     = (const float*)d_in[0];
  const float* ln_w  = (const float*)d_in[1];
  const float* Wq    = (const float*)d_in[2];
  const float* Wk    = (const float*)d_in[3];
  const float* Wv    = (const float*)d_in[4];
  const float* Wo    = (const float*)d_in[5];
  const float* gamma = (const float*)d_in[6];
  float* out = (float*)d_out;

  char* w = (char*)d_ws;
  short* Qf    = (short*)w;                               // 4 MB frag-major Q (pre-scaled)
  short* Kf    = (short*)(w + 4194304);                   // 4 MB frag-major K
  short* Vf    = (short*)(w + 2 * 4194304);               // 4 MB frag-major V'
  float* aqg   = (float*)(w + 3 * 4194304);               // 128 KB
  short* attnB = (short*)(w + 3 * 4194304 + 131072);      // 4 MB

  hipLaunchKernelGGL(k_qkv,  dim3(512),  dim3(256), 0, stream, x, ln_w, Wq, Wk, Wv, gamma, Qf, Kf, Vf, aqg);
  hipLaunchKernelGGL(k_attn, dim3(1024), dim3(512), 0, stream, Qf, Kf, Vf, aqg, gamma, attnB);
  hipLaunchKernelGGL(k_proj, dim3(256),  dim3(256), 0, stream, attnB, Wo, out);
}

// Round 17
// 40.115 us; speedup vs baseline: 1.5281x; 1.0124x over previous
//
#include <hip/hip_runtime.h>
#include <math.h>

typedef __attribute__((ext_vector_type(8))) short bf8;    // 8 x bf16 (bit pattern)
typedef __attribute__((ext_vector_type(4))) short s4v;    // 4 x bf16 (8B store)
typedef __attribute__((ext_vector_type(16))) float f16v;  // MFMA 32x32 accum
typedef __attribute__((ext_vector_type(4))) float f4v;
typedef __attribute__((ext_vector_type(4))) int i4v;

constexpr int CS = 2048;
constexpr float EPS = 1e-5f;
constexpr float LOG2E = 1.44269504088896f;

static __device__ inline short f2bf(float x) {
  union { float f; unsigned u; } v; v.f = x;
  unsigned r = (v.u + 0x7FFFu + ((v.u >> 16) & 1u)) >> 16;  // RNE
  return (short)r;
}
static __device__ inline float bf2f(short u) {
  union { unsigned u; float f; } v;
  v.u = ((unsigned)(unsigned short)u) << 16;
  return v.f;
}
static __device__ inline unsigned cvt_pk_bf16(float lo, float hi) {
  unsigned d;
  asm("v_cvt_pk_bf16_f32 %0, %1, %2" : "=v"(d) : "v"(lo), "v"(hi));
  return d;
}

// ---------------- fused LN + QKV projections (MFMA), in-block W transpose, frag-major outputs ----------------
// Q is pre-scaled by cg = gamma/4*log2e (folds the score scaling out of k_attn's hot loop).
__global__ __launch_bounds__(256) void k_qkv(const float* __restrict__ x, const float* __restrict__ ln_w,
                                             const float* __restrict__ Wq, const float* __restrict__ Wk,
                                             const float* __restrict__ Wv, const float* __restrict__ gamma,
                                             short* __restrict__ Qf, short* __restrict__ Kf,
                                             short* __restrict__ Vf, float* __restrict__ aqg) {
  __shared__ short WtL[3 * 64 * 72];   // [w][f][e pad72] bf16 — per-block transposed weights
  __shared__ short QtL[2 * 32 * 72];   // [strip][s 32][f pad72]
  __shared__ short KtL[2 * 32 * 72];
  __shared__ float q2s[64];
  __shared__ float bks[64];            // exp2(cgk * k2[row])
  int blk = blockIdx.x;
  int bh = blk & 15, st = blk >> 4;
  int b = bh >> 3, h = bh & 7;
  int t = threadIdx.x, wid = t >> 6, lane = t & 63;
  int l31 = lane & 31, g = lane >> 5;
  int sh = wid >> 1, fh = wid & 1;
  int f = fh * 32 + l31;

  // ---- cooperative W transpose -> WtL (4x4 subtile per thread per matrix; weights L2-hot) ----
  {
    int e0 = (t >> 4) * 4, f0 = (t & 15) * 4;
    const float* srcs[3];
    srcs[0] = Wq + h * 4096; srcs[1] = Wk + h * 4096; srcs[2] = Wv + h * 4096;
#pragma unroll
    for (int wsel = 0; wsel < 3; ++wsel) {
      const float* src = srcs[wsel];
      f4v r0 = *(const f4v*)&src[(e0 + 0) * 64 + f0];
      f4v r1 = *(const f4v*)&src[(e0 + 1) * 64 + f0];
      f4v r2 = *(const f4v*)&src[(e0 + 2) * 64 + f0];
      f4v r3 = *(const f4v*)&src[(e0 + 3) * 64 + f0];
      short* dst = &WtL[wsel * 4608];
      s4v c0, c1, c2, c3;
      c0[0] = f2bf(r0.x); c0[1] = f2bf(r1.x); c0[2] = f2bf(r2.x); c0[3] = f2bf(r3.x);
      c1[0] = f2bf(r0.y); c1[1] = f2bf(r1.y); c1[2] = f2bf(r2.y); c1[3] = f2bf(r3.y);
      c2[0] = f2bf(r0.z); c2[1] = f2bf(r1.z); c2[2] = f2bf(r2.z); c2[3] = f2bf(r3.z);
      c3[0] = f2bf(r0.w); c3[1] = f2bf(r1.w); c3[2] = f2bf(r2.w); c3[3] = f2bf(r3.w);
      *(s4v*)&dst[(f0 + 0) * 72 + e0] = c0;
      *(s4v*)&dst[(f0 + 1) * 72 + e0] = c1;
      *(s4v*)&dst[(f0 + 2) * 72 + e0] = c2;
      *(s4v*)&dst[(f0 + 3) * 72 + e0] = c3;
    }
  }

  // ---- in-register LayerNorm over this lane's row ----
  int row = b * CS + st * 64 + sh * 32 + l31;
  f4v xv[8];
#pragma unroll
  for (int ks = 0; ks < 4; ++ks) {
    xv[2 * ks]     = *(const f4v*)&x[row * 64 + ks * 16 + g * 8];
    xv[2 * ks + 1] = *(const f4v*)&x[row * 64 + ks * 16 + g * 8 + 4];
  }
  float s = 0.f;
#pragma unroll
  for (int m = 0; m < 8; ++m) s += xv[m].x + xv[m].y + xv[m].z + xv[m].w;
  s += __shfl_xor(s, 32, 64);
  float mu = s * (1.f / 64.f);
  float vs = 0.f;
#pragma unroll
  for (int m = 0; m < 8; ++m) {
#pragma unroll
    for (int j = 0; j < 4; ++j) { float d = xv[m][j] - mu; vs += d * d; }
  }
  vs += __shfl_xor(vs, 32, 64);
  float rs = rsqrtf(vs * (1.f / 64.f) + EPS);
  bf8 af[4];
#pragma unroll
  for (int ks = 0; ks < 4; ++ks) {
    f4v lw0 = *(const f4v*)&ln_w[ks * 16 + g * 8];
    f4v lw1 = *(const f4v*)&ln_w[ks * 16 + g * 8 + 4];
#pragma unroll
    for (int j = 0; j < 4; ++j) {
      af[ks][j]     = f2bf((xv[2 * ks][j] - mu) * rs * lw0[j]);
      af[ks][j + 4] = f2bf((xv[2 * ks + 1][j] - mu) * rs * lw1[j]);
    }
  }
  float gh = gamma[h];
  float cgk = -gh * 0.125f * LOG2E;       // -gamma/8 in log2 domain
  float cgq = gh * 0.25f * LOG2E;         // folded into Q: scores = exp2(ct) directly
  float icgq2 = 1.f / (cgq * cgq);        // to recover true q2 from scaled Q
  __syncthreads();                        // WtL ready

  // ---- Q -> LDS tile (PRE-SCALED by cgq) ----
  f16v cq; for (int i = 0; i < 16; ++i) cq[i] = 0.f;
#pragma unroll
  for (int ks = 0; ks < 4; ++ks) {
    bf8 bw = *(const bf8*)&WtL[0 * 4608 + f * 72 + ks * 16 + g * 8];
    cq = __builtin_amdgcn_mfma_f32_32x32x16_bf16(af[ks], bw, cq, 0, 0, 0);
  }
#pragma unroll
  for (int r = 0; r < 16; ++r) {
    int rl = (r & 3) + 8 * (r >> 2) + 4 * g;
    QtL[(sh * 32 + rl) * 72 + f] = f2bf(cq[r] * cgq);
  }
  // ---- K -> LDS tile ----
  f16v ck; for (int i = 0; i < 16; ++i) ck[i] = 0.f;
#pragma unroll
  for (int ks = 0; ks < 4; ++ks) {
    bf8 bw = *(const bf8*)&WtL[1 * 4608 + f * 72 + ks * 16 + g * 8];
    ck = __builtin_amdgcn_mfma_f32_32x32x16_bf16(af[ks], bw, ck, 0, 0, 0);
  }
#pragma unroll
  for (int r = 0; r < 16; ++r) {
    int rl = (r & 3) + 8 * (r >> 2) + 4 * g;
    KtL[(sh * 32 + rl) * 72 + f] = f2bf(ck[r]);
  }
  // ---- V (stays in regs) ----
  f16v cv; for (int i = 0; i < 16; ++i) cv[i] = 0.f;
#pragma unroll
  for (int ks = 0; ks < 4; ++ks) {
    bf8 bw = *(const bf8*)&WtL[2 * 4608 + f * 72 + ks * 16 + g * 8];
    cv = __builtin_amdgcn_mfma_f32_32x32x16_bf16(af[ks], bw, cv, 0, 0, 0);
  }
  __syncthreads();

  // ---- cooperative q2/k2 (4 threads/row) + per-row bk = exp2(cgk*k2) ----
  // QtL is cgq-scaled: true q2 = sq * icgq2.
  {
    int rw = t >> 2, q4 = t & 3;
    float sq = 0.f, sk = 0.f;
#pragma unroll
    for (int m = 0; m < 2; ++m) {
      bf8 vq = *(bf8*)&QtL[rw * 72 + q4 * 16 + m * 8];
      bf8 vk = *(bf8*)&KtL[rw * 72 + q4 * 16 + m * 8];
#pragma unroll
      for (int j = 0; j < 8; ++j) {
        float xq = bf2f(vq[j]); sq += xq * xq;
        float xk = bf2f(vk[j]); sk += xk * xk;
      }
    }
    sq += __shfl_xor(sq, 1, 64); sq += __shfl_xor(sq, 2, 64);
    sk += __shfl_xor(sk, 1, 64); sk += __shfl_xor(sk, 2, 64);
    if (q4 == 0) {
      q2s[rw] = sq * icgq2;
      bks[rw] = exp2f(cgk * sk);
    }
  }
  // ---- cooperative packed frag-major stores: Qf and Kf [bh][strip][ks][lane][8], 4x8B each ----
  {
    int ktloc = t >> 7, lm = (t >> 1) & 63, jh = t & 1;
#pragma unroll
    for (int ks = 0; ks < 4; ++ks) {
      int laddr = (ktloc * 32 + (lm & 31)) * 72 + ks * 16 + (lm >> 5) * 8 + jh * 4;
      int gaddr = ((bh * 64 + st * 2 + ktloc) * 4 + ks) * 512 + lm * 8 + jh * 4;
      *(s4v*)&Qf[gaddr] = *(s4v*)&QtL[laddr];
      *(s4v*)&Kf[gaddr] = *(s4v*)&KtL[laddr];
    }
  }
  __syncthreads();

  // ---- V' -> frag-major Vf[bh][kt][eh][ks2][lane][8], scaled by bks[row] ----
  int kt = st * 2 + sh;
#pragma unroll
  for (int m = 0; m < 4; ++m) {
    s4v pk;
#pragma unroll
    for (int c = 0; c < 4; ++c) {
      int rl = sh * 32 + c + 8 * m + 4 * g;
      pk[c] = f2bf(cv[m * 4 + c] * bks[rl]);
    }
    int addr = ((((bh * 64 + kt) * 2 + fh) * 2 + (m >> 1)) * 64 + (m & 1) * 32 + l31) * 8 + 4 * g;
    *(s4v*)&Vf[addr] = pk;
  }
  if (t < 64) {
    aqg[bh * CS + st * 64 + t] = exp2f(cgk * q2s[t]);
  }
}

// ---------------- fused causal RBF attention (MFMA, single-strip, permlane exchange, pre-scaled Q) ----------------
// All 8 frag loads issue at loop top (one latency window); unroll-2 lets the scheduler hoist the
// next iteration's independent loads under this iteration's MFMA/exp chain.
__global__ __launch_bounds__(512, 4) void k_attn(const short* __restrict__ Qf, const short* __restrict__ Kf,
                                                 const short* __restrict__ Vf, const float* __restrict__ aqg,
                                                 const float* __restrict__ gamma, short* __restrict__ attnB) {
  __shared__ float red4[4][64][37];
  int bid = blockIdx.x;
  int bh = ((bid & 7) << 1) | ((bid >> 3) & 1);  // bh pinned per XCD (L2 locality)
  int qt = 63 - (bid >> 4);                      // long q-strips dispatched first
  int b = bh >> 3, h = bh & 7;
  int t = threadIdx.x, w = t >> 6, lane = t & 63;
  int lam = lane & 31, g = lane >> 5;
  int L = qt + 1;
  int lo = (w * L) >> 3, hi = ((w + 1) * L) >> 3;
  int hiND = hi < qt ? hi : qt;                  // unmasked steps; only wave 7 owns kt==qt

  // Q B-frags (pre-scaled by cg in k_qkv): 4 coalesced 1KB loads
  bf8 qf[4];
#pragma unroll
  for (int ks = 0; ks < 4; ++ks) qf[ks] = *(const bf8*)&Qf[((bh * 64 + qt) * 4 + ks) * 512 + lane * 8];

  f16v oa0, oa1;
#pragma unroll
  for (int rr = 0; rr < 16; ++rr) { oa0[rr] = 0.f; oa1[rr] = 0.f; }

  const short* kfb = Kf + bh * 131072 + lane * 8;
  const short* vfb = Vf + bh * 131072 + lane * 8;

  // ---- unmasked main loop ----
#pragma unroll 2
  for (int kt = lo; kt < hiND; ++kt) {
    // all 8 coalesced frag loads issued together: one latency window per step
    const short* kp = kfb + kt * 2048;
    const short* vp = vfb + kt * 2048;
    bf8 ak0 = *(const bf8*)(kp);
    bf8 ak1 = *(const bf8*)(kp + 512);
    bf8 ak2 = *(const bf8*)(kp + 1024);
    bf8 ak3 = *(const bf8*)(kp + 1536);
    bf8 av00 = *(const bf8*)(vp);
    bf8 av01 = *(const bf8*)(vp + 512);
    bf8 av10 = *(const bf8*)(vp + 1024);
    bf8 av11 = *(const bf8*)(vp + 1536);

    f16v ct;
#pragma unroll
    for (int rr = 0; rr < 16; ++rr) ct[rr] = 0.f;
    __builtin_amdgcn_s_setprio(1);
    ct = __builtin_amdgcn_mfma_f32_32x32x16_bf16(ak0, qf[0], ct, 0, 0, 0);
    ct = __builtin_amdgcn_mfma_f32_32x32x16_bf16(ak1, qf[1], ct, 0, 0, 0);
    ct = __builtin_amdgcn_mfma_f32_32x32x16_bf16(ak2, qf[2], ct, 0, 0, 0);
    ct = __builtin_amdgcn_mfma_f32_32x32x16_bf16(ak3, qf[3], ct, 0, 0, 0);
    __builtin_amdgcn_s_setprio(0);

    // exp (Q pre-scaled: no multiply) + pack
    unsigned pkA[4], pkB[4];
#pragma unroll
    for (int m = 0; m < 4; ++m) {
      float e0 = exp2f(ct[4 * m + 0]);
      float e1 = exp2f(ct[4 * m + 1]);
      float e2 = exp2f(ct[4 * m + 2]);
      float e3 = exp2f(ct[4 * m + 3]);
      pkA[m] = cvt_pk_bf16(e0, e1);
      pkB[m] = cvt_pk_bf16(e2, e3);
    }
    __builtin_amdgcn_s_setprio(1);
#pragma unroll
    for (int ks2 = 0; ks2 < 2; ++ks2) {
      unsigned a0 = pkA[2 * ks2], a1 = pkA[2 * ks2 + 1];
      unsigned b0 = pkB[2 * ks2], b1 = pkB[2 * ks2 + 1];
      asm("v_permlane32_swap_b32 %0, %1" : "+v"(a0), "+v"(a1));   // vdst=pk_even -> word0; vsrc=pk_odd -> word2
      asm("v_permlane32_swap_b32 %0, %1" : "+v"(b0), "+v"(b1));
      i4v wv;
      wv.x = (int)a0; wv.y = (int)b0; wv.z = (int)a1; wv.w = (int)b1;
      bf8 bs = *(bf8*)&wv;
      oa0 = __builtin_amdgcn_mfma_f32_32x32x16_bf16(ks2 ? av01 : av00, bs, oa0, 0, 0, 0);
      oa1 = __builtin_amdgcn_mfma_f32_32x32x16_bf16(ks2 ? av11 : av10, bs, oa1, 0, 0, 0);
    }
    __builtin_amdgcn_s_setprio(0);
  }

  // ---- diagonal tile (wave 7 only): same body with causal mask ----
  if (hi > hiND) {
    int kt = qt;
    const short* kp = kfb + kt * 2048;
    const short* vp = vfb + kt * 2048;
    bf8 ak0 = *(const bf8*)(kp);
    bf8 ak1 = *(const bf8*)(kp + 512);
    bf8 ak2 = *(const bf8*)(kp + 1024);
    bf8 ak3 = *(const bf8*)(kp + 1536);
    bf8 av00 = *(const bf8*)(vp);
    bf8 av01 = *(const bf8*)(vp + 512);
    bf8 av10 = *(const bf8*)(vp + 1024);
    bf8 av11 = *(const bf8*)(vp + 1536);

    f16v ct;
#pragma unroll
    for (int rr = 0; rr < 16; ++rr) ct[rr] = 0.f;
    ct = __builtin_amdgcn_mfma_f32_32x32x16_bf16(ak0, qf[0], ct, 0, 0, 0);
    ct = __builtin_amdgcn_mfma_f32_32x32x16_bf16(ak1, qf[1], ct, 0, 0, 0);
    ct = __builtin_amdgcn_mfma_f32_32x32x16_bf16(ak2, qf[2], ct, 0, 0, 0);
    ct = __builtin_amdgcn_mfma_f32_32x32x16_bf16(ak3, qf[3], ct, 0, 0, 0);

    unsigned pkA[4], pkB[4];
#pragma unroll
    for (int m = 0; m < 4; ++m) {
      float sv[4];
#pragma unroll
      for (int ii = 0; ii < 4; ++ii) {
        int kloc = ii + 8 * m + 4 * g;
        float ev = exp2f(ct[4 * m + ii]);
        if (kloc > lam) ev = 0.f;
        sv[ii] = ev;
      }
      pkA[m] = cvt_pk_bf16(sv[0], sv[1]);
      pkB[m] = cvt_pk_bf16(sv[2], sv[3]);
    }
#pragma unroll
    for (int ks2 = 0; ks2 < 2; ++ks2) {
      unsigned a0 = pkA[2 * ks2], a1 = pkA[2 * ks2 + 1];
      unsigned b0 = pkB[2 * ks2], b1 = pkB[2 * ks2 + 1];
      asm("v_permlane32_swap_b32 %0, %1" : "+v"(a0), "+v"(a1));
      asm("v_permlane32_swap_b32 %0, %1" : "+v"(b0), "+v"(b1));
      i4v wv;
      wv.x = (int)a0; wv.y = (int)b0; wv.z = (int)a1; wv.w = (int)b1;
      bf8 bs = *(bf8*)&wv;
      oa0 = __builtin_amdgcn_mfma_f32_32x32x16_bf16(ks2 ? av01 : av00, bs, oa0, 0, 0, 0);
      oa1 = __builtin_amdgcn_mfma_f32_32x32x16_bf16(ks2 ? av11 : av10, bs, oa1, 0, 0, 0);
    }
  }

  // ---- epilogue: 8-way cross-wave reduce in LDS, apply aq, coalesced bf16 store ----
  if (w < 4) {
#pragma unroll
    for (int rr = 0; rr < 16; ++rr) {
      int e = (rr & 3) + 8 * (rr >> 2) + 4 * g;
      red4[w][e][lam] = oa0[rr];
      red4[w][e + 32][lam] = oa1[rr];
    }
  }
  __syncthreads();
  if (w >= 4) {
#pragma unroll
    for (int rr = 0; rr < 16; ++rr) {
      int e = (rr & 3) + 8 * (rr >> 2) + 4 * g;
      red4[w - 4][e][lam] += oa0[rr];
      red4[w - 4][e + 32][lam] += oa1[rr];
    }
  }
  __syncthreads();
  {
    int q = t >> 4, e0 = (t & 15) * 4;
    float aqv = aqg[bh * CS + qt * 32 + q];
    s4v ov;
#pragma unroll
    for (int jj = 0; jj < 4; ++jj) {
      float v = red4[0][e0 + jj][q] + red4[1][e0 + jj][q] + red4[2][e0 + jj][q] + red4[3][e0 + jj][q];
      ov[jj] = f2bf(v * aqv);
    }
    *(s4v*)&attnB[(b * CS + qt * 32 + q) * 512 + h * 64 + e0] = ov;
  }
}

// ---------------- output projection (MFMA, 256 blocks, direct f32 Wo with in-reg bf16 cast) ----------------
__global__ __launch_bounds__(256) void k_proj(const short* __restrict__ attnB, const float* __restrict__ Wo,
                                              float* __restrict__ out) {
  __shared__ float red[4][32][36];
  int blk = blockIdx.x, t = threadIdx.x;
  int rt = blk >> 1, fh2 = blk & 1;
  int r0 = rt * 32;
  int kw = t >> 6, lane = t & 63, l31 = lane & 31, g = lane >> 5;
  f16v c; for (int i = 0; i < 16; ++i) c[i] = 0.f;
  int arow = (r0 + l31) * 512;
  int fw = fh2 * 32 + l31;           // Wo row (output feature)
#pragma unroll
  for (int ks = 0; ks < 8; ++ks) {
    int k0 = kw * 128 + ks * 16 + g * 8;
    bf8 a = *(const bf8*)&attnB[arow + k0];
    f4v w0 = *(const f4v*)&Wo[fw * 512 + k0];
    f4v w1 = *(const f4v*)&Wo[fw * 512 + k0 + 4];
    i4v wp;
    wp.x = (int)cvt_pk_bf16(w0.x, w0.y);
    wp.y = (int)cvt_pk_bf16(w0.z, w0.w);
    wp.z = (int)cvt_pk_bf16(w1.x, w1.y);
    wp.w = (int)cvt_pk_bf16(w1.z, w1.w);
    bf8 bw = *(bf8*)&wp;
    c = __builtin_amdgcn_mfma_f32_32x32x16_bf16(a, bw, c, 0, 0, 0);
  }
#pragma unroll
  for (int rr = 0; rr < 16; ++rr) {
    int rw = (rr & 3) + 8 * (rr >> 2) + 4 * g;
    red[kw][rw][l31] = c[rr];
  }
  __syncthreads();
  {
    int rw = t >> 3, f4 = (t & 7) * 4;
    f4v sum;
#pragma unroll
    for (int j = 0; j < 4; ++j)
      sum[j] = red[0][rw][f4 + j] + red[1][rw][f4 + j] + red[2][rw][f4 + j] + red[3][rw][f4 + j];
    *(f4v*)&out[(r0 + rw) * 64 + fh2 * 32 + f4] = sum;
  }
}

extern "C" void kernel_launch(void* const* d_in, const int* in_sizes, int n_in,
                              void* d_out, int out_size, void* d_ws, size_t ws_size,
                              hipStream_t stream) {
  const float* x     = (const float*)d_in[0];
  const float* ln_w  = (const float*)d_in[1];
  const float* Wq    = (const float*)d_in[2];
  const float* Wk    = (const float*)d_in[3];
  const float* Wv    = (const float*)d_in[4];
  const float* Wo    = (const float*)d_in[5];
  const float* gamma = (const float*)d_in[6];
  float* out = (float*)d_out;

  char* w = (char*)d_ws;
  short* Qf    = (short*)w;                               // 4 MB frag-major Q (pre-scaled)
  short* Kf    = (short*)(w + 4194304);                   // 4 MB frag-major K
  short* Vf    = (short*)(w + 2 * 4194304);               // 4 MB frag-major V'
  float* aqg   = (float*)(w + 3 * 4194304);               // 128 KB
  short* attnB = (short*)(w + 3 * 4194304 + 131072);      // 4 MB

  hipLaunchKernelGGL(k_qkv,  dim3(512),  dim3(256), 0, stream, x, ln_w, Wq, Wk, Wv, gamma, Qf, Kf, Vf, aqg);
  hipLaunchKernelGGL(k_attn, dim3(1024), dim3(512), 0, stream, Qf, Kf, Vf, aqg, gamma, attnB);
  hipLaunchKernelGGL(k_proj, dim3(256),  dim3(256), 0, stream, attnB, Wo, out);
}